// Round 10
// baseline (207.160 us; speedup 1.0000x reference)
//
#include <hip/hip_runtime.h>
#include <math.h>

#define EMBED   256
#define M_HEADS 8
#define DVAL    32
#define LK      16
#define S_TOTAL 21760
#define NQ      8192
#define NROWS   (2 * NQ)          // 16384 total query rows
#define QBS     16                // queries per block (sample)

typedef __attribute__((ext_vector_type(8))) short s16x8;
typedef __attribute__((ext_vector_type(4))) short s16x4;
typedef __attribute__((ext_vector_type(4))) float f32x4;
typedef unsigned short u16;
typedef unsigned int   u32;

__device__ __forceinline__ short f2bf(float f) {
    unsigned u = __float_as_uint(f);
    u += 0x7fffu + ((u >> 16) & 1u);
    return (short)(u >> 16);
}
__device__ __forceinline__ float bf2f(short h) {
    return __uint_as_float(((unsigned)(u16)h) << 16);
}

// ---------------- workspace layout (float offsets) ----------------
#define V_OFF     0                      // value table, bf16: 11,141,120 shorts
#define V_FLTS    5570560
#define PA_OFF    (V_OFF + V_FLTS)       // (x,y,attn) fp32 triples
#define PA_FLTS   6291456
#define MID_OFF   (PA_OFF + PA_FLTS)     // mid bf16 [16384][256]
#define MID_FLTS  2097152
#define WHI_OFF   (MID_OFF + MID_FLTS)   // packed [W_off|W_attn] hi, C=384
#define WOA_FLTS  49152
#define WLO_OFF   (WHI_OFF + WOA_FLTS)
#define WV_OFF    (WLO_OFF + WOA_FLTS)   // packed W_val bf16, C=256
#define WO_OFF    (WV_OFF + 32768)       // packed W_out bf16, C=256

// ---------------------------------------------------------------------------
// prep_kernel (weight packs only): blocks 0..511 pack W_val/W_out (C=256),
// blocks 512..895 pack [W_off|W_attn] hi/lo (C=384).
// ---------------------------------------------------------------------------
__global__ __launch_bounds__(256) void prep_kernel(
    const float* __restrict__ W_off, const float* __restrict__ W_attn,
    u16* __restrict__ Whi,           u16* __restrict__ Wlo,
    const float* __restrict__ W_val, u16* __restrict__ Wv,
    const float* __restrict__ W_out, u16* __restrict__ Wo)
{
    const int b = blockIdx.x;
    const int t = threadIdx.x;

    if (b < 512) {                        // pack W_val / W_out (C=256)
        const int flat = b * 256 + t;                // 0..131071
        const int which = flat >> 16;                // 0: W_val, 1: W_out
        const int e = flat & 65535;
        const int k = e >> 8, c = e & 255;
        const float f = which ? W_out[k * 256 + c] : W_val[k * 256 + c];
        const int kt = k >> 5, qd = (k >> 3) & 3, j = k & 7;
        const int idx = (((kt * 256 + c) << 2) + qd) * 8 + j;
        (which ? Wo : Wv)[idx] = (u16)f2bf(f);
    } else {                              // pack [W_off|W_attn] hi/lo (C=384)
        const int flat = (b - 512) * 256 + t;        // 0..98303
        const int k = flat / 384, c = flat - k * 384;
        const float f = (c < 256) ? W_off[k * 256 + c] : W_attn[k * 128 + (c - 256)];
        const short h = f2bf(f);
        const short lo = f2bf(f - bf2f(h));
        const int kt = k >> 5, qd = (k >> 3) & 3, j = k & 7;
        const int idx = (((kt * 384 + c) << 2) + qd) * 8 + j;
        Whi[idx] = (u16)h;
        Wlo[idx] = (u16)lo;
    }
}

// ---------------------------------------------------------------------------
// Fused vproj+qproj (r10). Both bodies are the r8/r9-verified WIN forms,
// byte-identical math; only blockIdx mapping + LDS union changed.
// Even blocks -> vproj (LDS-staged A, B-resident, tile prefetch; ~5us/block),
// odd blocks -> qproj (LDS-staged hi/lo A + 2-deep B register double-buffer).
// Rationale: r4's fusion failed with two ~40us halves and no backfill slack;
// now v-blocks are ~4x shorter, so the 512 queued blocks backfill retiring
// v-slots -> wall ~ packed average instead of sum. LDS = 50688B union
// (qproj footprint; vproj uses first 8KB).
// ---------------------------------------------------------------------------
__global__ __launch_bounds__(256) void vq_kernel(
    const float* __restrict__ value,
    const float* __restrict__ vmask,
    const u16* __restrict__ Wvpk,
    const float* __restrict__ b_val,
    u16* __restrict__ v_out,
    const float* __restrict__ queries,
    const float* __restrict__ qgl,
    const u16* __restrict__ Whi, const u16* __restrict__ Wlo,
    const float* __restrict__ b_off, const float* __restrict__ b_attn,
    float* __restrict__ pa)
{
    __shared__ __align__(16) char lds[50688];

    const int t  = threadIdx.x;
    const int w  = t >> 6, l = t & 63;
    const int c  = l & 15, qd = l >> 4;

    if ((blockIdx.x & 1) == 0) {
        // ================= vproj body (vb = 0..511) =================
        u16* sA = (u16*)lds;            // 16 x 256 bf16, swizzled

        const int vb = blockIdx.x >> 1;
        const int c0 = w * 64;

        s16x8 B[8][4];
        #pragma unroll
        for (int kt = 0; kt < 8; ++kt)
            #pragma unroll
            for (int nt = 0; nt < 4; ++nt)
                B[kt][nt] = *(const s16x8*)(Wvpk + (((kt * 256 + c0 + nt * 16 + c) << 2) + qd) * 8);

        float bias[4];
        #pragma unroll
        for (int nt = 0; nt < 4; ++nt) bias[nt] = b_val[c0 + nt * 16 + c];

        const int srow = t >> 6;        // + i*4
        const int scol = 4 * (t & 63);

        int tile = vb;
        float4 st[4];
        {
            const float* __restrict__ vp = value + (size_t)tile * 16 * EMBED;
            #pragma unroll
            for (int i = 0; i < 4; ++i)
                st[i] = *(const float4*)(vp + (i * 4 + srow) * EMBED + scol);
        }

        for (;;) {
            #pragma unroll
            for (int i = 0; i < 4; ++i) {
                const int row = i * 4 + srow;
                const int idx = ((row << 8) + scol) ^ ((row & 7) << 3);
                *(s16x4*)(sA + idx) = (s16x4){ f2bf(st[i].x), f2bf(st[i].y),
                                               f2bf(st[i].z), f2bf(st[i].w) };
            }
            __syncthreads();

            const int r0   = tile * 16;
            const int next = tile + 512;
            if (next < 2720) {          // prefetch next tile under compute
                const float* __restrict__ vp = value + (size_t)next * 16 * EMBED;
                #pragma unroll
                for (int i = 0; i < 4; ++i)
                    st[i] = *(const float4*)(vp + (i * 4 + srow) * EMBED + scol);
            }

            f32x4 acc[4] = {};
            #pragma unroll
            for (int kt = 0; kt < 8; ++kt) {
                const s16x8 a = *(const s16x8*)(sA + ((((c << 8) + kt * 32 + qd * 8)) ^ ((c & 7) << 3)));
                #pragma unroll
                for (int nt = 0; nt < 4; ++nt)
                    acc[nt] = __builtin_amdgcn_mfma_f32_16x16x32_bf16(a, B[kt][nt], acc[nt], 0, 0, 0);
            }

            #pragma unroll
            for (int r = 0; r < 4; ++r) {
                const int grow = r0 + qd * 4 + r;
                const int n = (grow >= S_TOTAL) ? 1 : 0;
                const int s = grow - n * S_TOTAL;
                const float mk = vmask[grow];
                #pragma unroll
                for (int nt = 0; nt < 4; ++nt) {
                    const int col = c0 + nt * 16 + c;
                    const int hm = col >> 5, d = col & 31;
                    v_out[((size_t)(n * M_HEADS + hm) * S_TOTAL + s) * DVAL + d] =
                        (u16)f2bf((acc[nt][r] + bias[nt]) * mk);
                }
            }
            __syncthreads();
            if (next >= 2720) break;
            tile = next;
        }
    } else {
        // ================= qproj body (qb = 0..511) =================
        u16* sAh = (u16*)lds;                           // [32][256] swizzled
        u16* sAl = sAh + 8192;
        float (*s_off)[260]  = (float(*)[260])lds;      // aliases staging
        float (*s_attn)[132] = (float(*)[132])(lds + 33280);
        float (*s_geom)[4]   = (float(*)[4])(lds + 50176);

        const int qb   = blockIdx.x >> 1;
        const int row0 = qb * 32;
        const int c0   = w * 96;

        if (t < 32) {
            const float* g = &qgl[(size_t)(row0 + t) * 4];
            s_geom[t][0] = 1.f / (1.f + __expf(-g[0]));
            s_geom[t][1] = 1.f / (1.f + __expf(-g[1]));
            s_geom[t][2] = (1.f / (1.f + __expf(-g[2]))) * 0.125f;
            s_geom[t][3] = (1.f / (1.f + __expf(-g[3]))) * 0.125f;
        }

        {
            const int srow = t >> 6;    // + i*4
            const int scol = 4 * (t & 63);
            #pragma unroll
            for (int i = 0; i < 8; ++i) {
                const int row = i * 4 + srow;
                const float4 v = *(const float4*)(queries + (size_t)(row0 + row) * EMBED + scol);
                const short h0 = f2bf(v.x), h1 = f2bf(v.y), h2 = f2bf(v.z), h3 = f2bf(v.w);
                const int idx = ((row << 8) + scol) ^ ((row & 7) << 3);
                *(s16x4*)(sAh + idx) = (s16x4){ h0, h1, h2, h3 };
                *(s16x4*)(sAl + idx) = (s16x4){ f2bf(v.x - bf2f(h0)), f2bf(v.y - bf2f(h1)),
                                                f2bf(v.z - bf2f(h2)), f2bf(v.w - bf2f(h3)) };
            }
        }
        __syncthreads();

        f32x4 acc[2][6] = {};
        s16x8 bhA[6], blA[6], bhB[6], blB[6];

        auto loadB = [&](int kt, s16x8 (&bh)[6], s16x8 (&bl)[6]) {
            #pragma unroll
            for (int nt = 0; nt < 6; ++nt) {
                const int idx = (((kt * 384 + c0 + nt * 16 + c) << 2) + qd) * 8;
                bh[nt] = *(const s16x8*)(Whi + idx);
                bl[nt] = *(const s16x8*)(Wlo + idx);
            }
        };
        auto stepK = [&](int kt, s16x8 (&bh)[6], s16x8 (&bl)[6]) {
            s16x8 ah[2], al[2];
            #pragma unroll
            for (int mt = 0; mt < 2; ++mt) {
                const int row = mt * 16 + c;
                const int idx = ((row << 8) + kt * 32 + qd * 8) ^ ((row & 7) << 3);
                ah[mt] = *(const s16x8*)(sAh + idx);
                al[mt] = *(const s16x8*)(sAl + idx);
            }
            #pragma unroll
            for (int mt = 0; mt < 2; ++mt)
                #pragma unroll
                for (int nt = 0; nt < 6; ++nt) {
                    acc[mt][nt] = __builtin_amdgcn_mfma_f32_16x16x32_bf16(ah[mt], bh[nt], acc[mt][nt], 0, 0, 0);
                    acc[mt][nt] = __builtin_amdgcn_mfma_f32_16x16x32_bf16(ah[mt], bl[nt], acc[mt][nt], 0, 0, 0);
                    acc[mt][nt] = __builtin_amdgcn_mfma_f32_16x16x32_bf16(al[mt], bh[nt], acc[mt][nt], 0, 0, 0);
                }
        };

        loadB(0, bhA, blA);
        loadB(1, bhB, blB);
        #pragma unroll
        for (int kp = 0; kp < 4; ++kp) {
            stepK(2 * kp, bhA, blA);
            if (kp < 3) loadB(2 * kp + 2, bhA, blA);
            stepK(2 * kp + 1, bhB, blB);
            if (kp < 3) loadB(2 * kp + 3, bhB, blB);
        }
        __syncthreads();    // all LDS A-reads done before s_off overwrites staging

        #pragma unroll
        for (int mt = 0; mt < 2; ++mt)
            #pragma unroll
            for (int nt = 0; nt < 6; ++nt) {
                const int col = c0 + nt * 16 + c;
                #pragma unroll
                for (int r = 0; r < 4; ++r) {
                    const int row = mt * 16 + qd * 4 + r;
                    if (col < 256) s_off[row][col] = acc[mt][nt][r] + b_off[col];
                    else           s_attn[row][col - 256] = acc[mt][nt][r] + b_attn[col - 256];
                }
            }
        __syncthreads();

        {
            const int qi = t >> 3, hm = t & 7;
            float* a = &s_attn[qi][hm * LK];
            float mx = a[0];
            #pragma unroll
            for (int i = 1; i < LK; ++i) mx = fmaxf(mx, a[i]);
            float s = 0.f;
            #pragma unroll
            for (int i = 0; i < LK; ++i) { const float e = __expf(a[i] - mx); a[i] = e; s += e; }
            const float inv = 1.f / s;
            #pragma unroll
            for (int i = 0; i < LK; ++i) a[i] *= inv;
        }
        __syncthreads();

        for (int p = t; p < 32 * 128; p += 256) {
            const int qi = p >> 7;
            const int pt = p & 127;
            const int lvl = (pt & 15) >> 2;
            const float Wl = (float)(128 >> lvl);
            const float px = fmaf(s_off[qi][2 * pt + 0], s_geom[qi][2], s_geom[qi][0]);
            const float py = fmaf(s_off[qi][2 * pt + 1], s_geom[qi][3], s_geom[qi][1]);
            const float gx = fminf(fmaxf(2.f * px - 1.f, -1.f), 1.f);
            const float gy = fminf(fmaxf(2.f * py - 1.f, -1.f), 1.f);
            const float x = (gx + 1.f) * (Wl * 0.5f) - 0.5f;
            const float y = (gy + 1.f) * (Wl * 0.5f) - 0.5f;
            const size_t idx = ((size_t)(row0 + qi) * 128 + pt) * 3;
            pa[idx + 0] = x;
            pa[idx + 1] = y;
            pa[idx + 2] = s_attn[qi][pt];
        }
    }
}

// ---------------------------------------------------------------------------
// Kernel 3: bilinear sampling (r2-verified 4B-gather form). m = blk&7 keeps
// one head's slice L2-local per XCD. (r3: wider gathers don't help — cost
// scales with 64B segments, not instructions.)
// ---------------------------------------------------------------------------
__global__ __launch_bounds__(256) void sample_kernel(
    const float* __restrict__ pa,
    const u16* __restrict__ v_tab,
    u16* __restrict__ mid)
{
    __shared__ int4   s_idx[QBS * 17];
    __shared__ float4 s_w[QBS * 17];

    const int t    = threadIdx.x;
    const int m    = blockIdx.x & 7;
    const int rest = blockIdx.x >> 3;
    const int qc   = rest & 511;
    const int n    = rest >> 9;
    const int q0   = qc * QBS;

    {
        const int qi = t >> 4, lk = t & 15;
        const int lvl   = lk >> 2;
        const int Wl    = 128 >> lvl;
        const int start = (lvl == 0) ? 0 : (lvl == 1) ? 16384 : (lvl == 2) ? 20480 : 21504;

        const size_t prow = ((size_t)(n * NQ + q0 + qi)) * 128 + m * 16 + lk;
        const float x  = pa[prow * 3 + 0];
        const float y  = pa[prow * 3 + 1];
        const float aw = pa[prow * 3 + 2];

        const float x0f = floorf(x), y0f = floorf(y);
        const int   x0 = (int)x0f, y0 = (int)y0f;
        const float wx = x - x0f, wy = y - y0f;

        const float vx0 = (x0 >= 0) ? 1.f : 0.f;
        const float vx1 = (x0 + 1 <= Wl - 1) ? 1.f : 0.f;
        const float vy0 = (y0 >= 0) ? 1.f : 0.f;
        const float vy1 = (y0 + 1 <= Wl - 1) ? 1.f : 0.f;

        const int xc0 = max(x0, 0);
        const int xc1 = min(x0 + 1, Wl - 1);
        const int yc0 = max(y0, 0);
        const int yc1 = min(y0 + 1, Wl - 1);

        const int e = qi * 17 + lk;
        s_idx[e] = make_int4((start + yc0 * Wl + xc0) * DVAL,
                             (start + yc0 * Wl + xc1) * DVAL,
                             (start + yc1 * Wl + xc0) * DVAL,
                             (start + yc1 * Wl + xc1) * DVAL);
        s_w[e] = make_float4(aw * (1.f - wx) * (1.f - wy) * vx0 * vy0,
                             aw * wx * (1.f - wy) * vx1 * vy0,
                             aw * (1.f - wx) * wy * vx0 * vy1,
                             aw * wx * wy * vx1 * vy1);
    }
    __syncthreads();

    const int g = t >> 4, dp = t & 15;
    const u16* __restrict__ vbp =
        v_tab + (size_t)(n * M_HEADS + m) * S_TOTAL * DVAL + 2 * dp;

    float acc0 = 0.f, acc1 = 0.f;
    #pragma unroll
    for (int lk = 0; lk < LK; ++lk) {
        const int4   id = s_idx[g * 17 + lk];
        const float4 w  = s_w[g * 17 + lk];
        const u32 u0 = *(const u32*)(vbp + id.x);
        const u32 u1 = *(const u32*)(vbp + id.y);
        const u32 u2 = *(const u32*)(vbp + id.z);
        const u32 u3 = *(const u32*)(vbp + id.w);
        acc0 = fmaf(w.x, __uint_as_float(u0 << 16), acc0);
        acc1 = fmaf(w.x, __uint_as_float(u0 & 0xffff0000u), acc1);
        acc0 = fmaf(w.y, __uint_as_float(u1 << 16), acc0);
        acc1 = fmaf(w.y, __uint_as_float(u1 & 0xffff0000u), acc1);
        acc0 = fmaf(w.z, __uint_as_float(u2 << 16), acc0);
        acc1 = fmaf(w.z, __uint_as_float(u2 & 0xffff0000u), acc1);
        acc0 = fmaf(w.w, __uint_as_float(u3 << 16), acc0);
        acc1 = fmaf(w.w, __uint_as_float(u3 & 0xffff0000u), acc1);
    }

    const u32 packed = ((u32)(u16)f2bf(acc1) << 16) | (u32)(u16)f2bf(acc0);
    *(u32*)(mid + ((size_t)(n * NQ + q0 + g)) * EMBED + m * DVAL + 2 * dp) = packed;
}

// ---------------------------------------------------------------------------
// Kernel 4 (MFMA, B-resident): out = mid @ W_out + b_out. r2-verified form.
// ---------------------------------------------------------------------------
__global__ __launch_bounds__(256, 2) void out_kernel(
    const u16* __restrict__ mid,
    const u16* __restrict__ Wpk,
    const float* __restrict__ b_out,
    float* __restrict__ out)
{
    const int t  = threadIdx.x;
    const int w  = t >> 6, l = t & 63;
    const int c  = l & 15, qd = l >> 4;
    const int c0 = w * 64;

    s16x8 B[8][4];
    #pragma unroll
    for (int kt = 0; kt < 8; ++kt)
        #pragma unroll
        for (int nt = 0; nt < 4; ++nt)
            B[kt][nt] = *(const s16x8*)(Wpk + (((kt * 256 + c0 + nt * 16 + c) << 2) + qd) * 8);

    float bias[4];
    #pragma unroll
    for (int nt = 0; nt < 4; ++nt) bias[nt] = b_out[c0 + nt * 16 + c];

    for (int tile = blockIdx.x; tile < 1024; tile += 512) {
        const int r0 = tile * 16;
        const u16* __restrict__ ap = mid + (size_t)(r0 + c) * EMBED + qd * 8;

        s16x8 a[8];
        #pragma unroll
        for (int kt = 0; kt < 8; ++kt)
            a[kt] = *(const s16x8*)(ap + kt * 32);

        f32x4 acc[4] = {};
        #pragma unroll
        for (int kt = 0; kt < 8; ++kt)
            #pragma unroll
            for (int nt = 0; nt < 4; ++nt)
                acc[nt] = __builtin_amdgcn_mfma_f32_16x16x32_bf16(a[kt], B[kt][nt], acc[nt], 0, 0, 0);

        #pragma unroll
        for (int r = 0; r < 4; ++r) {
            const int row = r0 + qd * 4 + r;
            #pragma unroll
            for (int nt = 0; nt < 4; ++nt)
                out[(size_t)row * EMBED + c0 + nt * 16 + c] = acc[nt][r] + bias[nt];
        }
    }
}

// ---------------------------------------------------------------------------
extern "C" void kernel_launch(void* const* d_in, const int* in_sizes, int n_in,
                              void* d_out, int out_size, void* d_ws, size_t ws_size,
                              hipStream_t stream) {
    (void)in_sizes; (void)n_in; (void)out_size; (void)ws_size;

    const float* queries = (const float*)d_in[0];
    const float* qgl     = (const float*)d_in[1];
    const float* value   = (const float*)d_in[2];
    const float* vmask   = (const float*)d_in[3];
    const float* W_off   = (const float*)d_in[4];
    const float* b_off   = (const float*)d_in[5];
    const float* W_attn  = (const float*)d_in[6];
    const float* b_attn  = (const float*)d_in[7];
    const float* W_val   = (const float*)d_in[8];
    const float* b_val   = (const float*)d_in[9];
    const float* W_out   = (const float*)d_in[10];
    const float* b_out   = (const float*)d_in[11];

    float* ws   = (float*)d_ws;
    u16*  v_ws  = (u16*)(ws + V_OFF);
    float* pa   = ws + PA_OFF;
    u16*  mid   = (u16*)(ws + MID_OFF);
    u16*  whi   = (u16*)(ws + WHI_OFF);
    u16*  wlo   = (u16*)(ws + WLO_OFF);
    u16*  wvpk  = (u16*)(ws + WV_OFF);
    u16*  wopk  = (u16*)(ws + WO_OFF);
    float* outp = (float*)d_out;

    prep_kernel<<<896, 256, 0, stream>>>(W_off, W_attn, whi, wlo,
                                         W_val, wvpk, W_out, wopk);

    vq_kernel<<<1024, 256, 0, stream>>>(value, vmask, wvpk, b_val, v_ws,
                                        queries, qgl, whi, wlo,
                                        b_off, b_attn, pa);
    sample_kernel<<<2 * (NQ / QBS) * M_HEADS, 256, 0, stream>>>(pa, v_ws, mid);
    out_kernel<<<512, 256, 0, stream>>>(mid, wopk, b_out, outp);
}

// Round 11
// 192.827 us; speedup vs baseline: 1.0743x; 1.0743x over previous
//
#include <hip/hip_runtime.h>
#include <math.h>

#define EMBED   256
#define M_HEADS 8
#define DVAL    32
#define LK      16
#define S_TOTAL 21760
#define NQ      8192
#define NROWS   (2 * NQ)          // 16384 total query rows
#define QBS     16                // queries per block (sample)

typedef __attribute__((ext_vector_type(8))) short s16x8;
typedef __attribute__((ext_vector_type(4))) short s16x4;
typedef __attribute__((ext_vector_type(4))) float f32x4;
typedef unsigned short u16;
typedef unsigned int   u32;

__device__ __forceinline__ short f2bf(float f) {
    unsigned u = __float_as_uint(f);
    u += 0x7fffu + ((u >> 16) & 1u);
    return (short)(u >> 16);
}
__device__ __forceinline__ float bf2f(short h) {
    return __uint_as_float(((unsigned)(u16)h) << 16);
}

// ---------------- workspace layout (float offsets) ----------------
#define V_OFF     0                      // value table, bf16: 11,141,120 shorts
#define V_FLTS    5570560
#define PA_OFF    (V_OFF + V_FLTS)       // (x,y,attn) fp32 triples
#define PA_FLTS   6291456
#define MID_OFF   (PA_OFF + PA_FLTS)     // mid bf16 [16384][256]
#define MID_FLTS  2097152
#define WHI_OFF   (MID_OFF + MID_FLTS)   // packed [W_off|W_attn] hi, C=384
#define WOA_FLTS  49152
#define WLO_OFF   (WHI_OFF + WOA_FLTS)
#define WV_OFF    (WLO_OFF + WOA_FLTS)   // packed W_val bf16, C=256
#define WO_OFF    (WV_OFF + 32768)       // packed W_out bf16, C=256

// ---------------------------------------------------------------------------
// prep_kernel (weight packs only): blocks 0..511 pack W_val/W_out (C=256),
// blocks 512..895 pack [W_off|W_attn] hi/lo (C=384).
// ---------------------------------------------------------------------------
__global__ __launch_bounds__(256) void prep_kernel(
    const float* __restrict__ W_off, const float* __restrict__ W_attn,
    u16* __restrict__ Whi,           u16* __restrict__ Wlo,
    const float* __restrict__ W_val, u16* __restrict__ Wv,
    const float* __restrict__ W_out, u16* __restrict__ Wo)
{
    const int b = blockIdx.x;
    const int t = threadIdx.x;

    if (b < 512) {                        // pack W_val / W_out (C=256)
        const int flat = b * 256 + t;                // 0..131071
        const int which = flat >> 16;                // 0: W_val, 1: W_out
        const int e = flat & 65535;
        const int k = e >> 8, c = e & 255;
        const float f = which ? W_out[k * 256 + c] : W_val[k * 256 + c];
        const int kt = k >> 5, qd = (k >> 3) & 3, j = k & 7;
        const int idx = (((kt * 256 + c) << 2) + qd) * 8 + j;
        (which ? Wo : Wv)[idx] = (u16)f2bf(f);
    } else {                              // pack [W_off|W_attn] hi/lo (C=384)
        const int flat = (b - 512) * 256 + t;        // 0..98303
        const int k = flat / 384, c = flat - k * 384;
        const float f = (c < 256) ? W_off[k * 256 + c] : W_attn[k * 128 + (c - 256)];
        const short h = f2bf(f);
        const short lo = f2bf(f - bf2f(h));
        const int kt = k >> 5, qd = (k >> 3) & 3, j = k & 7;
        const int idx = (((kt * 384 + c) << 2) + qd) * 8 + j;
        Whi[idx] = (u16)h;
        Wlo[idx] = (u16)lo;
    }
}

// ---------------------------------------------------------------------------
// Kernel 1 (MFMA, B-resident, LDS-staged A): v = mask*(value@W_val + b_val).
// r8/r9-verified WIN form. (r4/r7/r10 lesson: do NOT fuse with qproj — three
// attempts all landed at ~71us from resource-union occupancy collapse.)
// ---------------------------------------------------------------------------
__global__ __launch_bounds__(256, 2) void vproj_kernel(
    const float* __restrict__ value,
    const float* __restrict__ vmask,
    const u16* __restrict__ Wpk,
    const float* __restrict__ b_val,
    u16* __restrict__ v_out)
{
    __shared__ u16 sA[4096];            // 16 rows x 256 cols bf16, swizzled

    const int t  = threadIdx.x;
    const int w  = t >> 6, l = t & 63;
    const int c  = l & 15, qd = l >> 4;
    const int c0 = w * 64;

    s16x8 B[8][4];
    #pragma unroll
    for (int kt = 0; kt < 8; ++kt)
        #pragma unroll
        for (int nt = 0; nt < 4; ++nt)
            B[kt][nt] = *(const s16x8*)(Wpk + (((kt * 256 + c0 + nt * 16 + c) << 2) + qd) * 8);

    float bias[4];
    #pragma unroll
    for (int nt = 0; nt < 4; ++nt) bias[nt] = b_val[c0 + nt * 16 + c];

    // staging geometry: thread t covers floats f = i*1024 + 4t of the tile
    const int srow = t >> 6;            // + i*4
    const int scol = 4 * (t & 63);

    int tile = blockIdx.x;
    float4 st[4];
    {
        const float* __restrict__ vp = value + (size_t)tile * 16 * EMBED;
        #pragma unroll
        for (int i = 0; i < 4; ++i)
            st[i] = *(const float4*)(vp + (i * 4 + srow) * EMBED + scol);
    }

    for (;;) {
        // convert + swizzled LDS write (each row's 512B: 2-way banks, free)
        #pragma unroll
        for (int i = 0; i < 4; ++i) {
            const int row = i * 4 + srow;
            const int idx = ((row << 8) + scol) ^ ((row & 7) << 3);
            *(s16x4*)(sA + idx) = (s16x4){ f2bf(st[i].x), f2bf(st[i].y),
                                           f2bf(st[i].z), f2bf(st[i].w) };
        }
        __syncthreads();

        const int r0   = tile * 16;
        const int next = tile + 512;
        if (next < 2720) {              // prefetch next tile under compute
            const float* __restrict__ vp = value + (size_t)next * 16 * EMBED;
            #pragma unroll
            for (int i = 0; i < 4; ++i)
                st[i] = *(const float4*)(vp + (i * 4 + srow) * EMBED + scol);
        }

        f32x4 acc[4] = {};
        #pragma unroll
        for (int kt = 0; kt < 8; ++kt) {
            const s16x8 a = *(const s16x8*)(sA + ((((c << 8) + kt * 32 + qd * 8)) ^ ((c & 7) << 3)));
            #pragma unroll
            for (int nt = 0; nt < 4; ++nt)
                acc[nt] = __builtin_amdgcn_mfma_f32_16x16x32_bf16(a, B[kt][nt], acc[nt], 0, 0, 0);
        }

        #pragma unroll
        for (int r = 0; r < 4; ++r) {
            const int grow = r0 + qd * 4 + r;
            const int n = (grow >= S_TOTAL) ? 1 : 0;
            const int s = grow - n * S_TOTAL;
            const float mk = vmask[grow];
            #pragma unroll
            for (int nt = 0; nt < 4; ++nt) {
                const int col = c0 + nt * 16 + c;
                const int hm = col >> 5, d = col & 31;
                v_out[((size_t)(n * M_HEADS + hm) * S_TOTAL + s) * DVAL + d] =
                    (u16)f2bf((acc[nt][r] + bias[nt]) * mk);
            }
        }
        __syncthreads();
        if (next >= 2720) break;
        tile = next;
    }
}

// ---------------------------------------------------------------------------
// Kernel 2 (split-bf16 MFMA, LDS-staged A + 2-deep B register double-buffer).
// r9-verified form (dropped qproj out of top-5, <40us).
// ---------------------------------------------------------------------------
__global__ __launch_bounds__(256) void qproj_kernel(
    const float* __restrict__ queries,
    const float* __restrict__ qgl,
    const u16* __restrict__ Whi, const u16* __restrict__ Wlo,
    const float* __restrict__ b_off, const float* __restrict__ b_attn,
    float* __restrict__ pa)
{
    __shared__ __align__(16) char s_un[33280];   // union: {Ah,Al bf16 32KB} then {s_off fp32 [32][260]}
    __shared__ float s_attn[32][132];
    __shared__ float s_geom[32][4];

    u16* sAh = (u16*)s_un;                       // [32][256] swizzled
    u16* sAl = sAh + 8192;
    float (*s_off)[260] = (float(*)[260])s_un;

    const int t  = threadIdx.x;
    const int w  = t >> 6, l = t & 63;
    const int c  = l & 15, qd = l >> 4;
    const int row0 = blockIdx.x * 32;
    const int c0 = w * 96;

    if (t < 32) {
        const float* g = &qgl[(size_t)(row0 + t) * 4];
        s_geom[t][0] = 1.f / (1.f + __expf(-g[0]));
        s_geom[t][1] = 1.f / (1.f + __expf(-g[1]));
        s_geom[t][2] = (1.f / (1.f + __expf(-g[2]))) * 0.125f;
        s_geom[t][3] = (1.f / (1.f + __expf(-g[3]))) * 0.125f;
    }

    // ---- stage queries 32x256 fp32 -> hi/lo bf16 LDS, once per block ----
    {
        const int srow = t >> 6;        // + i*4
        const int scol = 4 * (t & 63);
        #pragma unroll
        for (int i = 0; i < 8; ++i) {
            const int row = i * 4 + srow;
            const float4 v = *(const float4*)(queries + (size_t)(row0 + row) * EMBED + scol);
            const short h0 = f2bf(v.x), h1 = f2bf(v.y), h2 = f2bf(v.z), h3 = f2bf(v.w);
            const int idx = ((row << 8) + scol) ^ ((row & 7) << 3);
            *(s16x4*)(sAh + idx) = (s16x4){ h0, h1, h2, h3 };
            *(s16x4*)(sAl + idx) = (s16x4){ f2bf(v.x - bf2f(h0)), f2bf(v.y - bf2f(h1)),
                                            f2bf(v.z - bf2f(h2)), f2bf(v.w - bf2f(h3)) };
        }
    }
    __syncthreads();

    f32x4 acc[2][6] = {};

    // ---- k-loop with 2-deep register double-buffered B prefetch ----
    s16x8 bhA[6], blA[6], bhB[6], blB[6];

    auto loadB = [&](int kt, s16x8 (&bh)[6], s16x8 (&bl)[6]) {
        #pragma unroll
        for (int nt = 0; nt < 6; ++nt) {
            const int idx = (((kt * 384 + c0 + nt * 16 + c) << 2) + qd) * 8;
            bh[nt] = *(const s16x8*)(Whi + idx);
            bl[nt] = *(const s16x8*)(Wlo + idx);
        }
    };
    auto stepK = [&](int kt, s16x8 (&bh)[6], s16x8 (&bl)[6]) {
        s16x8 ah[2], al[2];
        #pragma unroll
        for (int mt = 0; mt < 2; ++mt) {
            const int row = mt * 16 + c;
            const int idx = ((row << 8) + kt * 32 + qd * 8) ^ ((row & 7) << 3);
            ah[mt] = *(const s16x8*)(sAh + idx);
            al[mt] = *(const s16x8*)(sAl + idx);
        }
        #pragma unroll
        for (int mt = 0; mt < 2; ++mt)
            #pragma unroll
            for (int nt = 0; nt < 6; ++nt) {
                acc[mt][nt] = __builtin_amdgcn_mfma_f32_16x16x32_bf16(ah[mt], bh[nt], acc[mt][nt], 0, 0, 0);
                acc[mt][nt] = __builtin_amdgcn_mfma_f32_16x16x32_bf16(ah[mt], bl[nt], acc[mt][nt], 0, 0, 0);
                acc[mt][nt] = __builtin_amdgcn_mfma_f32_16x16x32_bf16(al[mt], bh[nt], acc[mt][nt], 0, 0, 0);
            }
    };

    loadB(0, bhA, blA);
    loadB(1, bhB, blB);
    #pragma unroll
    for (int kp = 0; kp < 4; ++kp) {
        stepK(2 * kp, bhA, blA);
        if (kp < 3) loadB(2 * kp + 2, bhA, blA);
        stepK(2 * kp + 1, bhB, blB);
        if (kp < 3) loadB(2 * kp + 3, bhB, blB);
    }
    __syncthreads();    // all LDS A-reads done before s_off overwrites staging

    #pragma unroll
    for (int mt = 0; mt < 2; ++mt)
        #pragma unroll
        for (int nt = 0; nt < 6; ++nt) {
            const int col = c0 + nt * 16 + c;
            #pragma unroll
            for (int r = 0; r < 4; ++r) {
                const int row = mt * 16 + qd * 4 + r;
                if (col < 256) s_off[row][col] = acc[mt][nt][r] + b_off[col];
                else           s_attn[row][col - 256] = acc[mt][nt][r] + b_attn[col - 256];
            }
        }
    __syncthreads();

    {
        const int qi = t >> 3, hm = t & 7;
        float* a = &s_attn[qi][hm * LK];
        float mx = a[0];
        #pragma unroll
        for (int i = 1; i < LK; ++i) mx = fmaxf(mx, a[i]);
        float s = 0.f;
        #pragma unroll
        for (int i = 0; i < LK; ++i) { const float e = __expf(a[i] - mx); a[i] = e; s += e; }
        const float inv = 1.f / s;
        #pragma unroll
        for (int i = 0; i < LK; ++i) a[i] *= inv;
    }
    __syncthreads();

    for (int p = t; p < 32 * 128; p += 256) {
        const int qi = p >> 7;
        const int pt = p & 127;
        const int lvl = (pt & 15) >> 2;
        const float Wl = (float)(128 >> lvl);
        const float px = fmaf(s_off[qi][2 * pt + 0], s_geom[qi][2], s_geom[qi][0]);
        const float py = fmaf(s_off[qi][2 * pt + 1], s_geom[qi][3], s_geom[qi][1]);
        const float gx = fminf(fmaxf(2.f * px - 1.f, -1.f), 1.f);
        const float gy = fminf(fmaxf(2.f * py - 1.f, -1.f), 1.f);
        const float x = (gx + 1.f) * (Wl * 0.5f) - 0.5f;
        const float y = (gy + 1.f) * (Wl * 0.5f) - 0.5f;
        const size_t idx = ((size_t)(row0 + qi) * 128 + pt) * 3;
        pa[idx + 0] = x;
        pa[idx + 1] = y;
        pa[idx + 2] = s_attn[qi][pt];
    }
}

// ---------------------------------------------------------------------------
// Kernel 3: bilinear sampling, two-phase ILP variant. Same mechanism that
// won r9's qproj: issue ALL independent loads before any consumer. Phase A
// preloads the 16 id/w pairs from LDS into registers, then issues all 64
// dword gathers into u[16][4] (static indexing; ~64 in-flight ≈ vmcnt cap).
// Phase B drains with FMAs in the EXACT r2 order (lk ascending, corners
// x,y,z,w) => bit-identical. VGPR ~160 (3 waves/SIMD) traded for deep ILP.
// m = blk&7 keeps one head's slice L2-local per XCD.
// ---------------------------------------------------------------------------
__global__ __launch_bounds__(256) void sample_kernel(
    const float* __restrict__ pa,
    const u16* __restrict__ v_tab,
    u16* __restrict__ mid)
{
    __shared__ int4   s_idx[QBS * 17];
    __shared__ float4 s_w[QBS * 17];

    const int t    = threadIdx.x;
    const int m    = blockIdx.x & 7;
    const int rest = blockIdx.x >> 3;
    const int qc   = rest & 511;
    const int n    = rest >> 9;
    const int q0   = qc * QBS;

    {
        const int qi = t >> 4, lk = t & 15;
        const int lvl   = lk >> 2;
        const int Wl    = 128 >> lvl;
        const int start = (lvl == 0) ? 0 : (lvl == 1) ? 16384 : (lvl == 2) ? 20480 : 21504;

        const size_t prow = ((size_t)(n * NQ + q0 + qi)) * 128 + m * 16 + lk;
        const float x  = pa[prow * 3 + 0];
        const float y  = pa[prow * 3 + 1];
        const float aw = pa[prow * 3 + 2];

        const float x0f = floorf(x), y0f = floorf(y);
        const int   x0 = (int)x0f, y0 = (int)y0f;
        const float wx = x - x0f, wy = y - y0f;

        const float vx0 = (x0 >= 0) ? 1.f : 0.f;
        const float vx1 = (x0 + 1 <= Wl - 1) ? 1.f : 0.f;
        const float vy0 = (y0 >= 0) ? 1.f : 0.f;
        const float vy1 = (y0 + 1 <= Wl - 1) ? 1.f : 0.f;

        const int xc0 = max(x0, 0);
        const int xc1 = min(x0 + 1, Wl - 1);
        const int yc0 = max(y0, 0);
        const int yc1 = min(y0 + 1, Wl - 1);

        const int e = qi * 17 + lk;
        s_idx[e] = make_int4((start + yc0 * Wl + xc0) * DVAL,
                             (start + yc0 * Wl + xc1) * DVAL,
                             (start + yc1 * Wl + xc0) * DVAL,
                             (start + yc1 * Wl + xc1) * DVAL);
        s_w[e] = make_float4(aw * (1.f - wx) * (1.f - wy) * vx0 * vy0,
                             aw * wx * (1.f - wy) * vx1 * vy0,
                             aw * (1.f - wx) * wy * vx0 * vy1,
                             aw * wx * wy * vx1 * vy1);
    }
    __syncthreads();

    const int g = t >> 4, dp = t & 15;
    const u16* __restrict__ vbp =
        v_tab + (size_t)(n * M_HEADS + m) * S_TOTAL * DVAL + 2 * dp;

    // ---- phase A: preload id/w, then issue ALL 64 gathers ----
    int4   id[LK];
    float4 wv[LK];
    #pragma unroll
    for (int lk = 0; lk < LK; ++lk) {
        id[lk] = s_idx[g * 17 + lk];
        wv[lk] = s_w[g * 17 + lk];
    }

    u32 u[LK][4];
    #pragma unroll
    for (int lk = 0; lk < LK; ++lk) {
        u[lk][0] = *(const u32*)(vbp + id[lk].x);
        u[lk][1] = *(const u32*)(vbp + id[lk].y);
        u[lk][2] = *(const u32*)(vbp + id[lk].z);
        u[lk][3] = *(const u32*)(vbp + id[lk].w);
    }

    // ---- phase B: drain in the exact r2 FMA order ----
    float acc0 = 0.f, acc1 = 0.f;
    #pragma unroll
    for (int lk = 0; lk < LK; ++lk) {
        acc0 = fmaf(wv[lk].x, __uint_as_float(u[lk][0] << 16), acc0);
        acc1 = fmaf(wv[lk].x, __uint_as_float(u[lk][0] & 0xffff0000u), acc1);
        acc0 = fmaf(wv[lk].y, __uint_as_float(u[lk][1] << 16), acc0);
        acc1 = fmaf(wv[lk].y, __uint_as_float(u[lk][1] & 0xffff0000u), acc1);
        acc0 = fmaf(wv[lk].z, __uint_as_float(u[lk][2] << 16), acc0);
        acc1 = fmaf(wv[lk].z, __uint_as_float(u[lk][2] & 0xffff0000u), acc1);
        acc0 = fmaf(wv[lk].w, __uint_as_float(u[lk][3] << 16), acc0);
        acc1 = fmaf(wv[lk].w, __uint_as_float(u[lk][3] & 0xffff0000u), acc1);
    }

    const u32 packed = ((u32)(u16)f2bf(acc1) << 16) | (u32)(u16)f2bf(acc0);
    *(u32*)(mid + ((size_t)(n * NQ + q0 + g)) * EMBED + m * DVAL + 2 * dp) = packed;
}

// ---------------------------------------------------------------------------
// Kernel 4 (MFMA, B-resident): out = mid @ W_out + b_out. r2-verified form.
// ---------------------------------------------------------------------------
__global__ __launch_bounds__(256, 2) void out_kernel(
    const u16* __restrict__ mid,
    const u16* __restrict__ Wpk,
    const float* __restrict__ b_out,
    float* __restrict__ out)
{
    const int t  = threadIdx.x;
    const int w  = t >> 6, l = t & 63;
    const int c  = l & 15, qd = l >> 4;
    const int c0 = w * 64;

    s16x8 B[8][4];
    #pragma unroll
    for (int kt = 0; kt < 8; ++kt)
        #pragma unroll
        for (int nt = 0; nt < 4; ++nt)
            B[kt][nt] = *(const s16x8*)(Wpk + (((kt * 256 + c0 + nt * 16 + c) << 2) + qd) * 8);

    float bias[4];
    #pragma unroll
    for (int nt = 0; nt < 4; ++nt) bias[nt] = b_out[c0 + nt * 16 + c];

    for (int tile = blockIdx.x; tile < 1024; tile += 512) {
        const int r0 = tile * 16;
        const u16* __restrict__ ap = mid + (size_t)(r0 + c) * EMBED + qd * 8;

        s16x8 a[8];
        #pragma unroll
        for (int kt = 0; kt < 8; ++kt)
            a[kt] = *(const s16x8*)(ap + kt * 32);

        f32x4 acc[4] = {};
        #pragma unroll
        for (int kt = 0; kt < 8; ++kt)
            #pragma unroll
            for (int nt = 0; nt < 4; ++nt)
                acc[nt] = __builtin_amdgcn_mfma_f32_16x16x32_bf16(a[kt], B[kt][nt], acc[nt], 0, 0, 0);

        #pragma unroll
        for (int r = 0; r < 4; ++r) {
            const int row = r0 + qd * 4 + r;
            #pragma unroll
            for (int nt = 0; nt < 4; ++nt)
                out[(size_t)row * EMBED + c0 + nt * 16 + c] = acc[nt][r] + bias[nt];
        }
    }
}

// ---------------------------------------------------------------------------
extern "C" void kernel_launch(void* const* d_in, const int* in_sizes, int n_in,
                              void* d_out, int out_size, void* d_ws, size_t ws_size,
                              hipStream_t stream) {
    (void)in_sizes; (void)n_in; (void)out_size; (void)ws_size;

    const float* queries = (const float*)d_in[0];
    const float* qgl     = (const float*)d_in[1];
    const float* value   = (const float*)d_in[2];
    const float* vmask   = (const float*)d_in[3];
    const float* W_off   = (const float*)d_in[4];
    const float* b_off   = (const float*)d_in[5];
    const float* W_attn  = (const float*)d_in[6];
    const float* b_attn  = (const float*)d_in[7];
    const float* W_val   = (const float*)d_in[8];
    const float* b_val   = (const float*)d_in[9];
    const float* W_out   = (const float*)d_in[10];
    const float* b_out   = (const float*)d_in[11];

    float* ws   = (float*)d_ws;
    u16*  v_ws  = (u16*)(ws + V_OFF);
    float* pa   = ws + PA_OFF;
    u16*  mid   = (u16*)(ws + MID_OFF);
    u16*  whi   = (u16*)(ws + WHI_OFF);
    u16*  wlo   = (u16*)(ws + WLO_OFF);
    u16*  wvpk  = (u16*)(ws + WV_OFF);
    u16*  wopk  = (u16*)(ws + WO_OFF);
    float* outp = (float*)d_out;

    prep_kernel<<<896, 256, 0, stream>>>(W_off, W_attn, whi, wlo,
                                         W_val, wvpk, W_out, wopk);

    vproj_kernel<<<512, 256, 0, stream>>>(value, vmask, wvpk, b_val, v_ws);
    qproj_kernel<<<NROWS / 32, 256, 0, stream>>>(queries, qgl, whi, wlo,
                                                 b_off, b_attn, pa);
    sample_kernel<<<2 * (NQ / QBS) * M_HEADS, 256, 0, stream>>>(pa, v_ws, mid);
    out_kernel<<<512, 256, 0, stream>>>(mid, wopk, b_out, outp);
}

// Round 12
// 187.361 us; speedup vs baseline: 1.1057x; 1.0292x over previous
//
#include <hip/hip_runtime.h>
#include <math.h>

#define EMBED   256
#define M_HEADS 8
#define DVAL    32
#define LK      16
#define S_TOTAL 21760
#define NQ      8192
#define NROWS   (2 * NQ)          // 16384 total query rows
#define QBS     16                // queries per block (sample)

typedef __attribute__((ext_vector_type(8))) short s16x8;
typedef __attribute__((ext_vector_type(4))) short s16x4;
typedef __attribute__((ext_vector_type(4))) float f32x4;
typedef unsigned short u16;
typedef unsigned int   u32;

__device__ __forceinline__ short f2bf(float f) {
    unsigned u = __float_as_uint(f);
    u += 0x7fffu + ((u >> 16) & 1u);
    return (short)(u >> 16);
}
__device__ __forceinline__ float bf2f(short h) {
    return __uint_as_float(((unsigned)(u16)h) << 16);
}

// ---------------- workspace layout (float offsets) ----------------
#define V_OFF     0                      // value table, bf16: 11,141,120 shorts
#define V_FLTS    5570560
#define PA_OFF    (V_OFF + V_FLTS)       // (x,y,attn) fp32 triples
#define PA_FLTS   6291456
#define MID_OFF   (PA_OFF + PA_FLTS)     // mid bf16 [16384][256]
#define MID_FLTS  2097152
#define WHI_OFF   (MID_OFF + MID_FLTS)   // packed [W_off|W_attn] hi, C=384
#define WOA_FLTS  49152
#define WLO_OFF   (WHI_OFF + WOA_FLTS)
#define WV_OFF    (WLO_OFF + WOA_FLTS)   // packed W_val bf16, C=256
#define WO_OFF    (WV_OFF + 32768)       // packed W_out bf16, C=256

// ---------------------------------------------------------------------------
// prep_kernel (weight packs only): blocks 0..511 pack W_val/W_out (C=256),
// blocks 512..895 pack [W_off|W_attn] hi/lo (C=384).
// ---------------------------------------------------------------------------
__global__ __launch_bounds__(256) void prep_kernel(
    const float* __restrict__ W_off, const float* __restrict__ W_attn,
    u16* __restrict__ Whi,           u16* __restrict__ Wlo,
    const float* __restrict__ W_val, u16* __restrict__ Wv,
    const float* __restrict__ W_out, u16* __restrict__ Wo)
{
    const int b = blockIdx.x;
    const int t = threadIdx.x;

    if (b < 512) {                        // pack W_val / W_out (C=256)
        const int flat = b * 256 + t;                // 0..131071
        const int which = flat >> 16;                // 0: W_val, 1: W_out
        const int e = flat & 65535;
        const int k = e >> 8, c = e & 255;
        const float f = which ? W_out[k * 256 + c] : W_val[k * 256 + c];
        const int kt = k >> 5, qd = (k >> 3) & 3, j = k & 7;
        const int idx = (((kt * 256 + c) << 2) + qd) * 8 + j;
        (which ? Wo : Wv)[idx] = (u16)f2bf(f);
    } else {                              // pack [W_off|W_attn] hi/lo (C=384)
        const int flat = (b - 512) * 256 + t;        // 0..98303
        const int k = flat / 384, c = flat - k * 384;
        const float f = (c < 256) ? W_off[k * 256 + c] : W_attn[k * 128 + (c - 256)];
        const short h = f2bf(f);
        const short lo = f2bf(f - bf2f(h));
        const int kt = k >> 5, qd = (k >> 3) & 3, j = k & 7;
        const int idx = (((kt * 384 + c) << 2) + qd) * 8 + j;
        Whi[idx] = (u16)h;
        Wlo[idx] = (u16)lo;
    }
}

// ---------------------------------------------------------------------------
// Kernel 1 (MFMA, B-resident, LDS-staged A): v = mask*(value@W_val + b_val).
// r8/r9-verified WIN form. (r4/r7/r10 lesson: do NOT fuse with qproj — three
// attempts all landed at ~71us from resource-union occupancy collapse.)
// ---------------------------------------------------------------------------
__global__ __launch_bounds__(256, 2) void vproj_kernel(
    const float* __restrict__ value,
    const float* __restrict__ vmask,
    const u16* __restrict__ Wpk,
    const float* __restrict__ b_val,
    u16* __restrict__ v_out)
{
    __shared__ u16 sA[4096];            // 16 rows x 256 cols bf16, swizzled

    const int t  = threadIdx.x;
    const int w  = t >> 6, l = t & 63;
    const int c  = l & 15, qd = l >> 4;
    const int c0 = w * 64;

    s16x8 B[8][4];
    #pragma unroll
    for (int kt = 0; kt < 8; ++kt)
        #pragma unroll
        for (int nt = 0; nt < 4; ++nt)
            B[kt][nt] = *(const s16x8*)(Wpk + (((kt * 256 + c0 + nt * 16 + c) << 2) + qd) * 8);

    float bias[4];
    #pragma unroll
    for (int nt = 0; nt < 4; ++nt) bias[nt] = b_val[c0 + nt * 16 + c];

    // staging geometry: thread t covers floats f = i*1024 + 4t of the tile
    const int srow = t >> 6;            // + i*4
    const int scol = 4 * (t & 63);

    int tile = blockIdx.x;
    float4 st[4];
    {
        const float* __restrict__ vp = value + (size_t)tile * 16 * EMBED;
        #pragma unroll
        for (int i = 0; i < 4; ++i)
            st[i] = *(const float4*)(vp + (i * 4 + srow) * EMBED + scol);
    }

    for (;;) {
        // convert + swizzled LDS write (each row's 512B: 2-way banks, free)
        #pragma unroll
        for (int i = 0; i < 4; ++i) {
            const int row = i * 4 + srow;
            const int idx = ((row << 8) + scol) ^ ((row & 7) << 3);
            *(s16x4*)(sA + idx) = (s16x4){ f2bf(st[i].x), f2bf(st[i].y),
                                           f2bf(st[i].z), f2bf(st[i].w) };
        }
        __syncthreads();

        const int r0   = tile * 16;
        const int next = tile + 512;
        if (next < 2720) {              // prefetch next tile under compute
            const float* __restrict__ vp = value + (size_t)next * 16 * EMBED;
            #pragma unroll
            for (int i = 0; i < 4; ++i)
                st[i] = *(const float4*)(vp + (i * 4 + srow) * EMBED + scol);
        }

        f32x4 acc[4] = {};
        #pragma unroll
        for (int kt = 0; kt < 8; ++kt) {
            const s16x8 a = *(const s16x8*)(sA + ((((c << 8) + kt * 32 + qd * 8)) ^ ((c & 7) << 3)));
            #pragma unroll
            for (int nt = 0; nt < 4; ++nt)
                acc[nt] = __builtin_amdgcn_mfma_f32_16x16x32_bf16(a, B[kt][nt], acc[nt], 0, 0, 0);
        }

        #pragma unroll
        for (int r = 0; r < 4; ++r) {
            const int grow = r0 + qd * 4 + r;
            const int n = (grow >= S_TOTAL) ? 1 : 0;
            const int s = grow - n * S_TOTAL;
            const float mk = vmask[grow];
            #pragma unroll
            for (int nt = 0; nt < 4; ++nt) {
                const int col = c0 + nt * 16 + c;
                const int hm = col >> 5, d = col & 31;
                v_out[((size_t)(n * M_HEADS + hm) * S_TOTAL + s) * DVAL + d] =
                    (u16)f2bf((acc[nt][r] + bias[nt]) * mk);
            }
        }
        __syncthreads();
        if (next >= 2720) break;
        tile = next;
    }
}

// ---------------------------------------------------------------------------
// Kernel 2 (split-bf16 MFMA, LDS-staged A + 2-deep B register double-buffer).
// r9-verified form (dropped qproj out of top-5, <40us).
// ---------------------------------------------------------------------------
__global__ __launch_bounds__(256) void qproj_kernel(
    const float* __restrict__ queries,
    const float* __restrict__ qgl,
    const u16* __restrict__ Whi, const u16* __restrict__ Wlo,
    const float* __restrict__ b_off, const float* __restrict__ b_attn,
    float* __restrict__ pa)
{
    __shared__ __align__(16) char s_un[33280];   // union: {Ah,Al bf16 32KB} then {s_off fp32 [32][260]}
    __shared__ float s_attn[32][132];
    __shared__ float s_geom[32][4];

    u16* sAh = (u16*)s_un;                       // [32][256] swizzled
    u16* sAl = sAh + 8192;
    float (*s_off)[260] = (float(*)[260])s_un;

    const int t  = threadIdx.x;
    const int w  = t >> 6, l = t & 63;
    const int c  = l & 15, qd = l >> 4;
    const int row0 = blockIdx.x * 32;
    const int c0 = w * 96;

    if (t < 32) {
        const float* g = &qgl[(size_t)(row0 + t) * 4];
        s_geom[t][0] = 1.f / (1.f + __expf(-g[0]));
        s_geom[t][1] = 1.f / (1.f + __expf(-g[1]));
        s_geom[t][2] = (1.f / (1.f + __expf(-g[2]))) * 0.125f;
        s_geom[t][3] = (1.f / (1.f + __expf(-g[3]))) * 0.125f;
    }

    // ---- stage queries 32x256 fp32 -> hi/lo bf16 LDS, once per block ----
    {
        const int srow = t >> 6;        // + i*4
        const int scol = 4 * (t & 63);
        #pragma unroll
        for (int i = 0; i < 8; ++i) {
            const int row = i * 4 + srow;
            const float4 v = *(const float4*)(queries + (size_t)(row0 + row) * EMBED + scol);
            const short h0 = f2bf(v.x), h1 = f2bf(v.y), h2 = f2bf(v.z), h3 = f2bf(v.w);
            const int idx = ((row << 8) + scol) ^ ((row & 7) << 3);
            *(s16x4*)(sAh + idx) = (s16x4){ h0, h1, h2, h3 };
            *(s16x4*)(sAl + idx) = (s16x4){ f2bf(v.x - bf2f(h0)), f2bf(v.y - bf2f(h1)),
                                            f2bf(v.z - bf2f(h2)), f2bf(v.w - bf2f(h3)) };
        }
    }
    __syncthreads();

    f32x4 acc[2][6] = {};

    // ---- k-loop with 2-deep register double-buffered B prefetch ----
    s16x8 bhA[6], blA[6], bhB[6], blB[6];

    auto loadB = [&](int kt, s16x8 (&bh)[6], s16x8 (&bl)[6]) {
        #pragma unroll
        for (int nt = 0; nt < 6; ++nt) {
            const int idx = (((kt * 384 + c0 + nt * 16 + c) << 2) + qd) * 8;
            bh[nt] = *(const s16x8*)(Whi + idx);
            bl[nt] = *(const s16x8*)(Wlo + idx);
        }
    };
    auto stepK = [&](int kt, s16x8 (&bh)[6], s16x8 (&bl)[6]) {
        s16x8 ah[2], al[2];
        #pragma unroll
        for (int mt = 0; mt < 2; ++mt) {
            const int row = mt * 16 + c;
            const int idx = ((row << 8) + kt * 32 + qd * 8) ^ ((row & 7) << 3);
            ah[mt] = *(const s16x8*)(sAh + idx);
            al[mt] = *(const s16x8*)(sAl + idx);
        }
        #pragma unroll
        for (int mt = 0; mt < 2; ++mt)
            #pragma unroll
            for (int nt = 0; nt < 6; ++nt) {
                acc[mt][nt] = __builtin_amdgcn_mfma_f32_16x16x32_bf16(ah[mt], bh[nt], acc[mt][nt], 0, 0, 0);
                acc[mt][nt] = __builtin_amdgcn_mfma_f32_16x16x32_bf16(ah[mt], bl[nt], acc[mt][nt], 0, 0, 0);
                acc[mt][nt] = __builtin_amdgcn_mfma_f32_16x16x32_bf16(al[mt], bh[nt], acc[mt][nt], 0, 0, 0);
            }
    };

    loadB(0, bhA, blA);
    loadB(1, bhB, blB);
    #pragma unroll
    for (int kp = 0; kp < 4; ++kp) {
        stepK(2 * kp, bhA, blA);
        if (kp < 3) loadB(2 * kp + 2, bhA, blA);
        stepK(2 * kp + 1, bhB, blB);
        if (kp < 3) loadB(2 * kp + 3, bhB, blB);
    }
    __syncthreads();    // all LDS A-reads done before s_off overwrites staging

    #pragma unroll
    for (int mt = 0; mt < 2; ++mt)
        #pragma unroll
        for (int nt = 0; nt < 6; ++nt) {
            const int col = c0 + nt * 16 + c;
            #pragma unroll
            for (int r = 0; r < 4; ++r) {
                const int row = mt * 16 + qd * 4 + r;
                if (col < 256) s_off[row][col] = acc[mt][nt][r] + b_off[col];
                else           s_attn[row][col - 256] = acc[mt][nt][r] + b_attn[col - 256];
            }
        }
    __syncthreads();

    {
        const int qi = t >> 3, hm = t & 7;
        float* a = &s_attn[qi][hm * LK];
        float mx = a[0];
        #pragma unroll
        for (int i = 1; i < LK; ++i) mx = fmaxf(mx, a[i]);
        float s = 0.f;
        #pragma unroll
        for (int i = 0; i < LK; ++i) { const float e = __expf(a[i] - mx); a[i] = e; s += e; }
        const float inv = 1.f / s;
        #pragma unroll
        for (int i = 0; i < LK; ++i) a[i] *= inv;
    }
    __syncthreads();

    for (int p = t; p < 32 * 128; p += 256) {
        const int qi = p >> 7;
        const int pt = p & 127;
        const int lvl = (pt & 15) >> 2;
        const float Wl = (float)(128 >> lvl);
        const float px = fmaf(s_off[qi][2 * pt + 0], s_geom[qi][2], s_geom[qi][0]);
        const float py = fmaf(s_off[qi][2 * pt + 1], s_geom[qi][3], s_geom[qi][1]);
        const float gx = fminf(fmaxf(2.f * px - 1.f, -1.f), 1.f);
        const float gy = fminf(fmaxf(2.f * py - 1.f, -1.f), 1.f);
        const float x = (gx + 1.f) * (Wl * 0.5f) - 0.5f;
        const float y = (gy + 1.f) * (Wl * 0.5f) - 0.5f;
        const size_t idx = ((size_t)(row0 + qi) * 128 + pt) * 3;
        pa[idx + 0] = x;
        pa[idx + 1] = y;
        pa[idx + 2] = s_attn[qi][pt];
    }
}

// ---------------------------------------------------------------------------
// Kernel 3: bilinear sampling (r2-verified 4B-gather form). m = blk&7 keeps
// one head's slice L2-local per XCD. Characterized (r3, r11): L2-segment-
// throughput-bound — wider gathers and deeper explicit ILP both fail.
// ---------------------------------------------------------------------------
__global__ __launch_bounds__(256) void sample_kernel(
    const float* __restrict__ pa,
    const u16* __restrict__ v_tab,
    u16* __restrict__ mid)
{
    __shared__ int4   s_idx[QBS * 17];
    __shared__ float4 s_w[QBS * 17];

    const int t    = threadIdx.x;
    const int m    = blockIdx.x & 7;
    const int rest = blockIdx.x >> 3;
    const int qc   = rest & 511;
    const int n    = rest >> 9;
    const int q0   = qc * QBS;

    {
        const int qi = t >> 4, lk = t & 15;
        const int lvl   = lk >> 2;
        const int Wl    = 128 >> lvl;
        const int start = (lvl == 0) ? 0 : (lvl == 1) ? 16384 : (lvl == 2) ? 20480 : 21504;

        const size_t prow = ((size_t)(n * NQ + q0 + qi)) * 128 + m * 16 + lk;
        const float x  = pa[prow * 3 + 0];
        const float y  = pa[prow * 3 + 1];
        const float aw = pa[prow * 3 + 2];

        const float x0f = floorf(x), y0f = floorf(y);
        const int   x0 = (int)x0f, y0 = (int)y0f;
        const float wx = x - x0f, wy = y - y0f;

        const float vx0 = (x0 >= 0) ? 1.f : 0.f;
        const float vx1 = (x0 + 1 <= Wl - 1) ? 1.f : 0.f;
        const float vy0 = (y0 >= 0) ? 1.f : 0.f;
        const float vy1 = (y0 + 1 <= Wl - 1) ? 1.f : 0.f;

        const int xc0 = max(x0, 0);
        const int xc1 = min(x0 + 1, Wl - 1);
        const int yc0 = max(y0, 0);
        const int yc1 = min(y0 + 1, Wl - 1);

        const int e = qi * 17 + lk;
        s_idx[e] = make_int4((start + yc0 * Wl + xc0) * DVAL,
                             (start + yc0 * Wl + xc1) * DVAL,
                             (start + yc1 * Wl + xc0) * DVAL,
                             (start + yc1 * Wl + xc1) * DVAL);
        s_w[e] = make_float4(aw * (1.f - wx) * (1.f - wy) * vx0 * vy0,
                             aw * wx * (1.f - wy) * vx1 * vy0,
                             aw * (1.f - wx) * wy * vx0 * vy1,
                             aw * wx * wy * vx1 * vy1);
    }
    __syncthreads();

    const int g = t >> 4, dp = t & 15;
    const u16* __restrict__ vbp =
        v_tab + (size_t)(n * M_HEADS + m) * S_TOTAL * DVAL + 2 * dp;

    float acc0 = 0.f, acc1 = 0.f;
    #pragma unroll
    for (int lk = 0; lk < LK; ++lk) {
        const int4   id = s_idx[g * 17 + lk];
        const float4 w  = s_w[g * 17 + lk];
        const u32 u0 = *(const u32*)(vbp + id.x);
        const u32 u1 = *(const u32*)(vbp + id.y);
        const u32 u2 = *(const u32*)(vbp + id.z);
        const u32 u3 = *(const u32*)(vbp + id.w);
        acc0 = fmaf(w.x, __uint_as_float(u0 << 16), acc0);
        acc1 = fmaf(w.x, __uint_as_float(u0 & 0xffff0000u), acc1);
        acc0 = fmaf(w.y, __uint_as_float(u1 << 16), acc0);
        acc1 = fmaf(w.y, __uint_as_float(u1 & 0xffff0000u), acc1);
        acc0 = fmaf(w.z, __uint_as_float(u2 << 16), acc0);
        acc1 = fmaf(w.z, __uint_as_float(u2 & 0xffff0000u), acc1);
        acc0 = fmaf(w.w, __uint_as_float(u3 << 16), acc0);
        acc1 = fmaf(w.w, __uint_as_float(u3 & 0xffff0000u), acc1);
    }

    const u32 packed = ((u32)(u16)f2bf(acc1) << 16) | (u32)(u16)f2bf(acc0);
    *(u32*)(mid + ((size_t)(n * NQ + q0 + g)) * EMBED + m * DVAL + 2 * dp) = packed;
}

// ---------------------------------------------------------------------------
// Kernel 4 (MFMA, B-resident): out = mid @ W_out + b_out. r2-verified form.
// ---------------------------------------------------------------------------
__global__ __launch_bounds__(256, 2) void out_kernel(
    const u16* __restrict__ mid,
    const u16* __restrict__ Wpk,
    const float* __restrict__ b_out,
    float* __restrict__ out)
{
    const int t  = threadIdx.x;
    const int w  = t >> 6, l = t & 63;
    const int c  = l & 15, qd = l >> 4;
    const int c0 = w * 64;

    s16x8 B[8][4];
    #pragma unroll
    for (int kt = 0; kt < 8; ++kt)
        #pragma unroll
        for (int nt = 0; nt < 4; ++nt)
            B[kt][nt] = *(const s16x8*)(Wpk + (((kt * 256 + c0 + nt * 16 + c) << 2) + qd) * 8);

    float bias[4];
    #pragma unroll
    for (int nt = 0; nt < 4; ++nt) bias[nt] = b_out[c0 + nt * 16 + c];

    for (int tile = blockIdx.x; tile < 1024; tile += 512) {
        const int r0 = tile * 16;
        const u16* __restrict__ ap = mid + (size_t)(r0 + c) * EMBED + qd * 8;

        s16x8 a[8];
        #pragma unroll
        for (int kt = 0; kt < 8; ++kt)
            a[kt] = *(const s16x8*)(ap + kt * 32);

        f32x4 acc[4] = {};
        #pragma unroll
        for (int kt = 0; kt < 8; ++kt)
            #pragma unroll
            for (int nt = 0; nt < 4; ++nt)
                acc[nt] = __builtin_amdgcn_mfma_f32_16x16x32_bf16(a[kt], B[kt][nt], acc[nt], 0, 0, 0);

        #pragma unroll
        for (int r = 0; r < 4; ++r) {
            const int row = r0 + qd * 4 + r;
            #pragma unroll
            for (int nt = 0; nt < 4; ++nt)
                out[(size_t)row * EMBED + c0 + nt * 16 + c] = acc[nt][r] + bias[nt];
        }
    }
}

// ---------------------------------------------------------------------------
extern "C" void kernel_launch(void* const* d_in, const int* in_sizes, int n_in,
                              void* d_out, int out_size, void* d_ws, size_t ws_size,
                              hipStream_t stream) {
    (void)in_sizes; (void)n_in; (void)out_size; (void)ws_size;

    const float* queries = (const float*)d_in[0];
    const float* qgl     = (const float*)d_in[1];
    const float* value   = (const float*)d_in[2];
    const float* vmask   = (const float*)d_in[3];
    const float* W_off   = (const float*)d_in[4];
    const float* b_off   = (const float*)d_in[5];
    const float* W_attn  = (const float*)d_in[6];
    const float* b_attn  = (const float*)d_in[7];
    const float* W_val   = (const float*)d_in[8];
    const float* b_val   = (const float*)d_in[9];
    const float* W_out   = (const float*)d_in[10];
    const float* b_out   = (const float*)d_in[11];

    float* ws   = (float*)d_ws;
    u16*  v_ws  = (u16*)(ws + V_OFF);
    float* pa   = ws + PA_OFF;
    u16*  mid   = (u16*)(ws + MID_OFF);
    u16*  whi   = (u16*)(ws + WHI_OFF);
    u16*  wlo   = (u16*)(ws + WLO_OFF);
    u16*  wvpk  = (u16*)(ws + WV_OFF);
    u16*  wopk  = (u16*)(ws + WO_OFF);
    float* outp = (float*)d_out;

    prep_kernel<<<896, 256, 0, stream>>>(W_off, W_attn, whi, wlo,
                                         W_val, wvpk, W_out, wopk);

    vproj_kernel<<<512, 256, 0, stream>>>(value, vmask, wvpk, b_val, v_ws);
    qproj_kernel<<<NROWS / 32, 256, 0, stream>>>(queries, qgl, whi, wlo,
                                                 b_off, b_attn, pa);
    sample_kernel<<<2 * (NQ / QBS) * M_HEADS, 256, 0, stream>>>(pa, v_ws, mid);
    out_kernel<<<512, 256, 0, stream>>>(mid, wopk, b_out, outp);
}

// Round 13
// 182.574 us; speedup vs baseline: 1.1347x; 1.0262x over previous
//
#include <hip/hip_runtime.h>
#include <math.h>

#define EMBED   256
#define M_HEADS 8
#define DVAL    32
#define LK      16
#define S_TOTAL 21760
#define NQ      8192
#define NROWS   (2 * NQ)          // 16384 total query rows
#define QBS     16                // queries per block (sample)

typedef __attribute__((ext_vector_type(8))) short s16x8;
typedef __attribute__((ext_vector_type(4))) short s16x4;
typedef __attribute__((ext_vector_type(4))) float f32x4;
typedef unsigned short u16;
typedef unsigned int   u32;

__device__ __forceinline__ short f2bf(float f) {
    unsigned u = __float_as_uint(f);
    u += 0x7fffu + ((u >> 16) & 1u);
    return (short)(u >> 16);
}
__device__ __forceinline__ float bf2f(short h) {
    return __uint_as_float(((unsigned)(u16)h) << 16);
}

// ---------------- workspace layout (float offsets) ----------------
#define V_OFF     0                      // value table, bf16: 11,141,120 shorts
#define V_FLTS    5570560
#define PA_OFF    (V_OFF + V_FLTS)       // (x,y,attn) fp32 triples
#define PA_FLTS   6291456
#define MID_OFF   (PA_OFF + PA_FLTS)     // mid bf16 [16384][256]
#define MID_FLTS  2097152
#define WHI_OFF   (MID_OFF + MID_FLTS)   // packed [W_off|W_attn] hi, C=384
#define WOA_FLTS  49152
#define WLO_OFF   (WHI_OFF + WOA_FLTS)
#define WV_OFF    (WLO_OFF + WOA_FLTS)   // packed W_val bf16, C=256
#define WO_OFF    (WV_OFF + 32768)       // packed W_out bf16, C=256

// ---------------------------------------------------------------------------
// prep_kernel (weight packs only): blocks 0..511 pack W_val/W_out (C=256),
// blocks 512..895 pack [W_off|W_attn] hi/lo (C=384).
// ---------------------------------------------------------------------------
__global__ __launch_bounds__(256) void prep_kernel(
    const float* __restrict__ W_off, const float* __restrict__ W_attn,
    u16* __restrict__ Whi,           u16* __restrict__ Wlo,
    const float* __restrict__ W_val, u16* __restrict__ Wv,
    const float* __restrict__ W_out, u16* __restrict__ Wo)
{
    const int b = blockIdx.x;
    const int t = threadIdx.x;

    if (b < 512) {                        // pack W_val / W_out (C=256)
        const int flat = b * 256 + t;                // 0..131071
        const int which = flat >> 16;                // 0: W_val, 1: W_out
        const int e = flat & 65535;
        const int k = e >> 8, c = e & 255;
        const float f = which ? W_out[k * 256 + c] : W_val[k * 256 + c];
        const int kt = k >> 5, qd = (k >> 3) & 3, j = k & 7;
        const int idx = (((kt * 256 + c) << 2) + qd) * 8 + j;
        (which ? Wo : Wv)[idx] = (u16)f2bf(f);
    } else {                              // pack [W_off|W_attn] hi/lo (C=384)
        const int flat = (b - 512) * 256 + t;        // 0..98303
        const int k = flat / 384, c = flat - k * 384;
        const float f = (c < 256) ? W_off[k * 256 + c] : W_attn[k * 128 + (c - 256)];
        const short h = f2bf(f);
        const short lo = f2bf(f - bf2f(h));
        const int kt = k >> 5, qd = (k >> 3) & 3, j = k & 7;
        const int idx = (((kt * 384 + c) << 2) + qd) * 8 + j;
        Whi[idx] = (u16)h;
        Wlo[idx] = (u16)lo;
    }
}

// ---------------------------------------------------------------------------
// Kernel 1 (MFMA, B-resident, LDS-staged A): v = mask*(value@W_val + b_val).
// r8/r9-verified WIN form. (r4/r7/r10 lesson: do NOT fuse with qproj — three
// attempts all landed at ~71us from resource-union occupancy collapse.)
// ---------------------------------------------------------------------------
__global__ __launch_bounds__(256, 2) void vproj_kernel(
    const float* __restrict__ value,
    const float* __restrict__ vmask,
    const u16* __restrict__ Wpk,
    const float* __restrict__ b_val,
    u16* __restrict__ v_out)
{
    __shared__ u16 sA[4096];            // 16 rows x 256 cols bf16, swizzled

    const int t  = threadIdx.x;
    const int w  = t >> 6, l = t & 63;
    const int c  = l & 15, qd = l >> 4;
    const int c0 = w * 64;

    s16x8 B[8][4];
    #pragma unroll
    for (int kt = 0; kt < 8; ++kt)
        #pragma unroll
        for (int nt = 0; nt < 4; ++nt)
            B[kt][nt] = *(const s16x8*)(Wpk + (((kt * 256 + c0 + nt * 16 + c) << 2) + qd) * 8);

    float bias[4];
    #pragma unroll
    for (int nt = 0; nt < 4; ++nt) bias[nt] = b_val[c0 + nt * 16 + c];

    // staging geometry: thread t covers floats f = i*1024 + 4t of the tile
    const int srow = t >> 6;            // + i*4
    const int scol = 4 * (t & 63);

    int tile = blockIdx.x;
    float4 st[4];
    {
        const float* __restrict__ vp = value + (size_t)tile * 16 * EMBED;
        #pragma unroll
        for (int i = 0; i < 4; ++i)
            st[i] = *(const float4*)(vp + (i * 4 + srow) * EMBED + scol);
    }

    for (;;) {
        // convert + swizzled LDS write (each row's 512B: 2-way banks, free)
        #pragma unroll
        for (int i = 0; i < 4; ++i) {
            const int row = i * 4 + srow;
            const int idx = ((row << 8) + scol) ^ ((row & 7) << 3);
            *(s16x4*)(sA + idx) = (s16x4){ f2bf(st[i].x), f2bf(st[i].y),
                                           f2bf(st[i].z), f2bf(st[i].w) };
        }
        __syncthreads();

        const int r0   = tile * 16;
        const int next = tile + 512;
        if (next < 2720) {              // prefetch next tile under compute
            const float* __restrict__ vp = value + (size_t)next * 16 * EMBED;
            #pragma unroll
            for (int i = 0; i < 4; ++i)
                st[i] = *(const float4*)(vp + (i * 4 + srow) * EMBED + scol);
        }

        f32x4 acc[4] = {};
        #pragma unroll
        for (int kt = 0; kt < 8; ++kt) {
            const s16x8 a = *(const s16x8*)(sA + ((((c << 8) + kt * 32 + qd * 8)) ^ ((c & 7) << 3)));
            #pragma unroll
            for (int nt = 0; nt < 4; ++nt)
                acc[nt] = __builtin_amdgcn_mfma_f32_16x16x32_bf16(a, B[kt][nt], acc[nt], 0, 0, 0);
        }

        #pragma unroll
        for (int r = 0; r < 4; ++r) {
            const int grow = r0 + qd * 4 + r;
            const int n = (grow >= S_TOTAL) ? 1 : 0;
            const int s = grow - n * S_TOTAL;
            const float mk = vmask[grow];
            #pragma unroll
            for (int nt = 0; nt < 4; ++nt) {
                const int col = c0 + nt * 16 + c;
                const int hm = col >> 5, d = col & 31;
                v_out[((size_t)(n * M_HEADS + hm) * S_TOTAL + s) * DVAL + d] =
                    (u16)f2bf((acc[nt][r] + bias[nt]) * mk);
            }
        }
        __syncthreads();
        if (next >= 2720) break;
        tile = next;
    }
}

// ---------------------------------------------------------------------------
// Kernel 2 (split-bf16 MFMA): 64-rows-per-wave variant. r12 theory: qproj's
// stall source is the per-wave B-stream (reuse factor = rows/wave = 32 ->
// 196 MB of latency-exposed L2 reads). Doubling rows/wave to 64 halves it
// (98 MB) — the same amortization mechanism as the session's two wins.
// Shape: grid 256, 512 threads = 8 waves x 48 cols, each wave 64 rows
// (mt=0..3). LDS ~101 KB (union: 64KB hi/lo staging aliased by s_off
// [64][260]): 1 block/CU, 2 waves/SIMD. acc[4][3]+2-deep B dbuf ~150 VGPR.
// Per-output accumulation order (kt asc x hi*bh, hi*bl, lo*bh) unchanged
// => bit-identical to r9.
// ---------------------------------------------------------------------------
__global__ __launch_bounds__(512) void qproj_kernel(
    const float* __restrict__ queries,
    const float* __restrict__ qgl,
    const u16* __restrict__ Whi, const u16* __restrict__ Wlo,
    const float* __restrict__ b_off, const float* __restrict__ b_attn,
    float* __restrict__ pa)
{
    __shared__ __align__(16) char s_un[66560];   // union: {Ah,Al bf16 64KB} then {s_off fp32 [64][260]}
    __shared__ float s_attn[64][132];
    __shared__ float s_geom[64][4];

    u16* sAh = (u16*)s_un;                       // [64][256] swizzled
    u16* sAl = sAh + 16384;
    float (*s_off)[260] = (float(*)[260])s_un;

    const int t  = threadIdx.x;
    const int w  = t >> 6, l = t & 63;
    const int c  = l & 15, qd = l >> 4;
    const int row0 = blockIdx.x * 64;
    const int c0 = w * 48;

    if (t < 64) {
        const float* g = &qgl[(size_t)(row0 + t) * 4];
        s_geom[t][0] = 1.f / (1.f + __expf(-g[0]));
        s_geom[t][1] = 1.f / (1.f + __expf(-g[1]));
        s_geom[t][2] = (1.f / (1.f + __expf(-g[2]))) * 0.125f;
        s_geom[t][3] = (1.f / (1.f + __expf(-g[3]))) * 0.125f;
    }

    // ---- stage queries 64x256 fp32 -> hi/lo bf16 LDS, once per block ----
    {
        const int srow = t >> 6;        // + i*8
        const int scol = 4 * (t & 63);
        #pragma unroll
        for (int i = 0; i < 8; ++i) {
            const int row = i * 8 + srow;
            const float4 v = *(const float4*)(queries + (size_t)(row0 + row) * EMBED + scol);
            const short h0 = f2bf(v.x), h1 = f2bf(v.y), h2 = f2bf(v.z), h3 = f2bf(v.w);
            const int idx = ((row << 8) + scol) ^ ((row & 7) << 3);
            *(s16x4*)(sAh + idx) = (s16x4){ h0, h1, h2, h3 };
            *(s16x4*)(sAl + idx) = (s16x4){ f2bf(v.x - bf2f(h0)), f2bf(v.y - bf2f(h1)),
                                            f2bf(v.z - bf2f(h2)), f2bf(v.w - bf2f(h3)) };
        }
    }
    __syncthreads();

    f32x4 acc[4][3] = {};

    // ---- k-loop with 2-deep register double-buffered B prefetch ----
    s16x8 bhA[3], blA[3], bhB[3], blB[3];

    auto loadB = [&](int kt, s16x8 (&bh)[3], s16x8 (&bl)[3]) {
        #pragma unroll
        for (int nt = 0; nt < 3; ++nt) {
            const int idx = (((kt * 384 + c0 + nt * 16 + c) << 2) + qd) * 8;
            bh[nt] = *(const s16x8*)(Whi + idx);
            bl[nt] = *(const s16x8*)(Wlo + idx);
        }
    };
    auto stepK = [&](int kt, s16x8 (&bh)[3], s16x8 (&bl)[3]) {
        s16x8 ah[4], al[4];
        #pragma unroll
        for (int mt = 0; mt < 4; ++mt) {
            const int row = mt * 16 + c;
            const int idx = ((row << 8) + kt * 32 + qd * 8) ^ ((row & 7) << 3);
            ah[mt] = *(const s16x8*)(sAh + idx);
            al[mt] = *(const s16x8*)(sAl + idx);
        }
        #pragma unroll
        for (int mt = 0; mt < 4; ++mt)
            #pragma unroll
            for (int nt = 0; nt < 3; ++nt) {
                acc[mt][nt] = __builtin_amdgcn_mfma_f32_16x16x32_bf16(ah[mt], bh[nt], acc[mt][nt], 0, 0, 0);
                acc[mt][nt] = __builtin_amdgcn_mfma_f32_16x16x32_bf16(ah[mt], bl[nt], acc[mt][nt], 0, 0, 0);
                acc[mt][nt] = __builtin_amdgcn_mfma_f32_16x16x32_bf16(al[mt], bh[nt], acc[mt][nt], 0, 0, 0);
            }
    };

    loadB(0, bhA, blA);
    loadB(1, bhB, blB);
    #pragma unroll
    for (int kp = 0; kp < 4; ++kp) {
        stepK(2 * kp, bhA, blA);
        if (kp < 3) loadB(2 * kp + 2, bhA, blA);
        stepK(2 * kp + 1, bhB, blB);
        if (kp < 3) loadB(2 * kp + 3, bhB, blB);
    }
    __syncthreads();    // all LDS A-reads done before s_off overwrites staging

    #pragma unroll
    for (int mt = 0; mt < 4; ++mt)
        #pragma unroll
        for (int nt = 0; nt < 3; ++nt) {
            const int col = c0 + nt * 16 + c;
            #pragma unroll
            for (int r = 0; r < 4; ++r) {
                const int row = mt * 16 + qd * 4 + r;
                if (col < 256) s_off[row][col] = acc[mt][nt][r] + b_off[col];
                else           s_attn[row][col - 256] = acc[mt][nt][r] + b_attn[col - 256];
            }
        }
    __syncthreads();

    {   // 512 threads = exactly 64 rows x 8 heads softmax tasks
        const int qi = t >> 3, hm = t & 7;
        float* a = &s_attn[qi][hm * LK];
        float mx = a[0];
        #pragma unroll
        for (int i = 1; i < LK; ++i) mx = fmaxf(mx, a[i]);
        float s = 0.f;
        #pragma unroll
        for (int i = 0; i < LK; ++i) { const float e = __expf(a[i] - mx); a[i] = e; s += e; }
        const float inv = 1.f / s;
        #pragma unroll
        for (int i = 0; i < LK; ++i) a[i] *= inv;
    }
    __syncthreads();

    for (int p = t; p < 64 * 128; p += 512) {
        const int qi = p >> 7;
        const int pt = p & 127;
        const int lvl = (pt & 15) >> 2;
        const float Wl = (float)(128 >> lvl);
        const float px = fmaf(s_off[qi][2 * pt + 0], s_geom[qi][2], s_geom[qi][0]);
        const float py = fmaf(s_off[qi][2 * pt + 1], s_geom[qi][3], s_geom[qi][1]);
        const float gx = fminf(fmaxf(2.f * px - 1.f, -1.f), 1.f);
        const float gy = fminf(fmaxf(2.f * py - 1.f, -1.f), 1.f);
        const float x = (gx + 1.f) * (Wl * 0.5f) - 0.5f;
        const float y = (gy + 1.f) * (Wl * 0.5f) - 0.5f;
        const size_t idx = ((size_t)(row0 + qi) * 128 + pt) * 3;
        pa[idx + 0] = x;
        pa[idx + 1] = y;
        pa[idx + 2] = s_attn[qi][pt];
    }
}

// ---------------------------------------------------------------------------
// Kernel 3: bilinear sampling (r2-verified 4B-gather form). m = blk&7 keeps
// one head's slice L2-local per XCD. Characterized (r3, r11): L2-segment-
// throughput-bound — wider gathers and deeper explicit ILP both fail.
// ---------------------------------------------------------------------------
__global__ __launch_bounds__(256) void sample_kernel(
    const float* __restrict__ pa,
    const u16* __restrict__ v_tab,
    u16* __restrict__ mid)
{
    __shared__ int4   s_idx[QBS * 17];
    __shared__ float4 s_w[QBS * 17];

    const int t    = threadIdx.x;
    const int m    = blockIdx.x & 7;
    const int rest = blockIdx.x >> 3;
    const int qc   = rest & 511;
    const int n    = rest >> 9;
    const int q0   = qc * QBS;

    {
        const int qi = t >> 4, lk = t & 15;
        const int lvl   = lk >> 2;
        const int Wl    = 128 >> lvl;
        const int start = (lvl == 0) ? 0 : (lvl == 1) ? 16384 : (lvl == 2) ? 20480 : 21504;

        const size_t prow = ((size_t)(n * NQ + q0 + qi)) * 128 + m * 16 + lk;
        const float x  = pa[prow * 3 + 0];
        const float y  = pa[prow * 3 + 1];
        const float aw = pa[prow * 3 + 2];

        const float x0f = floorf(x), y0f = floorf(y);
        const int   x0 = (int)x0f, y0 = (int)y0f;
        const float wx = x - x0f, wy = y - y0f;

        const float vx0 = (x0 >= 0) ? 1.f : 0.f;
        const float vx1 = (x0 + 1 <= Wl - 1) ? 1.f : 0.f;
        const float vy0 = (y0 >= 0) ? 1.f : 0.f;
        const float vy1 = (y0 + 1 <= Wl - 1) ? 1.f : 0.f;

        const int xc0 = max(x0, 0);
        const int xc1 = min(x0 + 1, Wl - 1);
        const int yc0 = max(y0, 0);
        const int yc1 = min(y0 + 1, Wl - 1);

        const int e = qi * 17 + lk;
        s_idx[e] = make_int4((start + yc0 * Wl + xc0) * DVAL,
                             (start + yc0 * Wl + xc1) * DVAL,
                             (start + yc1 * Wl + xc0) * DVAL,
                             (start + yc1 * Wl + xc1) * DVAL);
        s_w[e] = make_float4(aw * (1.f - wx) * (1.f - wy) * vx0 * vy0,
                             aw * wx * (1.f - wy) * vx1 * vy0,
                             aw * (1.f - wx) * wy * vx0 * vy1,
                             aw * wx * wy * vx1 * vy1);
    }
    __syncthreads();

    const int g = t >> 4, dp = t & 15;
    const u16* __restrict__ vbp =
        v_tab + (size_t)(n * M_HEADS + m) * S_TOTAL * DVAL + 2 * dp;

    float acc0 = 0.f, acc1 = 0.f;
    #pragma unroll
    for (int lk = 0; lk < LK; ++lk) {
        const int4   id = s_idx[g * 17 + lk];
        const float4 w  = s_w[g * 17 + lk];
        const u32 u0 = *(const u32*)(vbp + id.x);
        const u32 u1 = *(const u32*)(vbp + id.y);
        const u32 u2 = *(const u32*)(vbp + id.z);
        const u32 u3 = *(const u32*)(vbp + id.w);
        acc0 = fmaf(w.x, __uint_as_float(u0 << 16), acc0);
        acc1 = fmaf(w.x, __uint_as_float(u0 & 0xffff0000u), acc1);
        acc0 = fmaf(w.y, __uint_as_float(u1 << 16), acc0);
        acc1 = fmaf(w.y, __uint_as_float(u1 & 0xffff0000u), acc1);
        acc0 = fmaf(w.z, __uint_as_float(u2 << 16), acc0);
        acc1 = fmaf(w.z, __uint_as_float(u2 & 0xffff0000u), acc1);
        acc0 = fmaf(w.w, __uint_as_float(u3 << 16), acc0);
        acc1 = fmaf(w.w, __uint_as_float(u3 & 0xffff0000u), acc1);
    }

    const u32 packed = ((u32)(u16)f2bf(acc1) << 16) | (u32)(u16)f2bf(acc0);
    *(u32*)(mid + ((size_t)(n * NQ + q0 + g)) * EMBED + m * DVAL + 2 * dp) = packed;
}

// ---------------------------------------------------------------------------
// Kernel 4 (MFMA, B-resident): out = mid @ W_out + b_out. r2-verified form.
// ---------------------------------------------------------------------------
__global__ __launch_bounds__(256, 2) void out_kernel(
    const u16* __restrict__ mid,
    const u16* __restrict__ Wpk,
    const float* __restrict__ b_out,
    float* __restrict__ out)
{
    const int t  = threadIdx.x;
    const int w  = t >> 6, l = t & 63;
    const int c  = l & 15, qd = l >> 4;
    const int c0 = w * 64;

    s16x8 B[8][4];
    #pragma unroll
    for (int kt = 0; kt < 8; ++kt)
        #pragma unroll
        for (int nt = 0; nt < 4; ++nt)
            B[kt][nt] = *(const s16x8*)(Wpk + (((kt * 256 + c0 + nt * 16 + c) << 2) + qd) * 8);

    float bias[4];
    #pragma unroll
    for (int nt = 0; nt < 4; ++nt) bias[nt] = b_out[c0 + nt * 16 + c];

    for (int tile = blockIdx.x; tile < 1024; tile += 512) {
        const int r0 = tile * 16;
        const u16* __restrict__ ap = mid + (size_t)(r0 + c) * EMBED + qd * 8;

        s16x8 a[8];
        #pragma unroll
        for (int kt = 0; kt < 8; ++kt)
            a[kt] = *(const s16x8*)(ap + kt * 32);

        f32x4 acc[4] = {};
        #pragma unroll
        for (int kt = 0; kt < 8; ++kt)
            #pragma unroll
            for (int nt = 0; nt < 4; ++nt)
                acc[nt] = __builtin_amdgcn_mfma_f32_16x16x32_bf16(a[kt], B[kt][nt], acc[nt], 0, 0, 0);

        #pragma unroll
        for (int r = 0; r < 4; ++r) {
            const int row = r0 + qd * 4 + r;
            #pragma unroll
            for (int nt = 0; nt < 4; ++nt)
                out[(size_t)row * EMBED + c0 + nt * 16 + c] = acc[nt][r] + bias[nt];
        }
    }
}

// ---------------------------------------------------------------------------
extern "C" void kernel_launch(void* const* d_in, const int* in_sizes, int n_in,
                              void* d_out, int out_size, void* d_ws, size_t ws_size,
                              hipStream_t stream) {
    (void)in_sizes; (void)n_in; (void)out_size; (void)ws_size;

    const float* queries = (const float*)d_in[0];
    const float* qgl     = (const float*)d_in[1];
    const float* value   = (const float*)d_in[2];
    const float* vmask   = (const float*)d_in[3];
    const float* W_off   = (const float*)d_in[4];
    const float* b_off   = (const float*)d_in[5];
    const float* W_attn  = (const float*)d_in[6];
    const float* b_attn  = (const float*)d_in[7];
    const float* W_val   = (const float*)d_in[8];
    const float* b_val   = (const float*)d_in[9];
    const float* W_out   = (const float*)d_in[10];
    const float* b_out   = (const float*)d_in[11];

    float* ws   = (float*)d_ws;
    u16*  v_ws  = (u16*)(ws + V_OFF);
    float* pa   = ws + PA_OFF;
    u16*  mid   = (u16*)(ws + MID_OFF);
    u16*  whi   = (u16*)(ws + WHI_OFF);
    u16*  wlo   = (u16*)(ws + WLO_OFF);
    u16*  wvpk  = (u16*)(ws + WV_OFF);
    u16*  wopk  = (u16*)(ws + WO_OFF);
    float* outp = (float*)d_out;

    prep_kernel<<<896, 256, 0, stream>>>(W_off, W_attn, whi, wlo,
                                         W_val, wvpk, W_out, wopk);

    vproj_kernel<<<512, 256, 0, stream>>>(value, vmask, wvpk, b_val, v_ws);
    qproj_kernel<<<NROWS / 64, 512, 0, stream>>>(queries, qgl, whi, wlo,
                                                 b_off, b_attn, pa);
    sample_kernel<<<2 * (NQ / QBS) * M_HEADS, 256, 0, stream>>>(pa, v_ws, mid);
    out_kernel<<<512, 256, 0, stream>>>(mid, wopk, b_out, outp);
}

// Round 14
// 180.141 us; speedup vs baseline: 1.1500x; 1.0135x over previous
//
#include <hip/hip_runtime.h>
#include <math.h>

#define EMBED   256
#define M_HEADS 8
#define DVAL    32
#define LK      16
#define S_TOTAL 21760
#define NQ      8192
#define NROWS   (2 * NQ)          // 16384 total query rows
#define QBS     16                // queries per block (sample)

typedef __attribute__((ext_vector_type(8))) short s16x8;
typedef __attribute__((ext_vector_type(4))) short s16x4;
typedef __attribute__((ext_vector_type(4))) float f32x4;
typedef unsigned short u16;
typedef unsigned int   u32;

__device__ __forceinline__ short f2bf(float f) {
    unsigned u = __float_as_uint(f);
    u += 0x7fffu + ((u >> 16) & 1u);
    return (short)(u >> 16);
}
__device__ __forceinline__ float bf2f(short h) {
    return __uint_as_float(((unsigned)(u16)h) << 16);
}

// ---------------- workspace layout (float offsets) ----------------
#define V_OFF     0                      // value table, bf16: 11,141,120 shorts
#define V_FLTS    5570560
#define PA_OFF    (V_OFF + V_FLTS)       // (x,y,attn) fp32 triples
#define PA_FLTS   6291456
#define MID_OFF   (PA_OFF + PA_FLTS)     // mid bf16 [16384][256]
#define MID_FLTS  2097152
#define WHI_OFF   (MID_OFF + MID_FLTS)   // packed [W_off|W_attn] hi, C=384
#define WOA_FLTS  49152
#define WLO_OFF   (WHI_OFF + WOA_FLTS)
#define WV_OFF    (WLO_OFF + WOA_FLTS)   // packed W_val bf16, C=256
#define WO_OFF    (WV_OFF + 32768)       // packed W_out bf16, C=256

// ---------------------------------------------------------------------------
// prep_kernel (weight packs only): blocks 0..511 pack W_val/W_out (C=256),
// blocks 512..895 pack [W_off|W_attn] hi/lo (C=384).
// ---------------------------------------------------------------------------
__global__ __launch_bounds__(256) void prep_kernel(
    const float* __restrict__ W_off, const float* __restrict__ W_attn,
    u16* __restrict__ Whi,           u16* __restrict__ Wlo,
    const float* __restrict__ W_val, u16* __restrict__ Wv,
    const float* __restrict__ W_out, u16* __restrict__ Wo)
{
    const int b = blockIdx.x;
    const int t = threadIdx.x;

    if (b < 512) {                        // pack W_val / W_out (C=256)
        const int flat = b * 256 + t;                // 0..131071
        const int which = flat >> 16;                // 0: W_val, 1: W_out
        const int e = flat & 65535;
        const int k = e >> 8, c = e & 255;
        const float f = which ? W_out[k * 256 + c] : W_val[k * 256 + c];
        const int kt = k >> 5, qd = (k >> 3) & 3, j = k & 7;
        const int idx = (((kt * 256 + c) << 2) + qd) * 8 + j;
        (which ? Wo : Wv)[idx] = (u16)f2bf(f);
    } else {                              // pack [W_off|W_attn] hi/lo (C=384)
        const int flat = (b - 512) * 256 + t;        // 0..98303
        const int k = flat / 384, c = flat - k * 384;
        const float f = (c < 256) ? W_off[k * 256 + c] : W_attn[k * 128 + (c - 256)];
        const short h = f2bf(f);
        const short lo = f2bf(f - bf2f(h));
        const int kt = k >> 5, qd = (k >> 3) & 3, j = k & 7;
        const int idx = (((kt * 384 + c) << 2) + qd) * 8 + j;
        Whi[idx] = (u16)h;
        Wlo[idx] = (u16)lo;
    }
}

// ---------------------------------------------------------------------------
// Kernel 1 (MFMA, B-resident, LDS-staged A): v = mask*(value@W_val + b_val).
// r8/r9-verified WIN form. (r4/r7/r10 lesson: do NOT fuse with qproj — three
// attempts all landed at ~71us from resource-union occupancy collapse.)
// ---------------------------------------------------------------------------
__global__ __launch_bounds__(256, 2) void vproj_kernel(
    const float* __restrict__ value,
    const float* __restrict__ vmask,
    const u16* __restrict__ Wpk,
    const float* __restrict__ b_val,
    u16* __restrict__ v_out)
{
    __shared__ u16 sA[4096];            // 16 rows x 256 cols bf16, swizzled

    const int t  = threadIdx.x;
    const int w  = t >> 6, l = t & 63;
    const int c  = l & 15, qd = l >> 4;
    const int c0 = w * 64;

    s16x8 B[8][4];
    #pragma unroll
    for (int kt = 0; kt < 8; ++kt)
        #pragma unroll
        for (int nt = 0; nt < 4; ++nt)
            B[kt][nt] = *(const s16x8*)(Wpk + (((kt * 256 + c0 + nt * 16 + c) << 2) + qd) * 8);

    float bias[4];
    #pragma unroll
    for (int nt = 0; nt < 4; ++nt) bias[nt] = b_val[c0 + nt * 16 + c];

    // staging geometry: thread t covers floats f = i*1024 + 4t of the tile
    const int srow = t >> 6;            // + i*4
    const int scol = 4 * (t & 63);

    int tile = blockIdx.x;
    float4 st[4];
    {
        const float* __restrict__ vp = value + (size_t)tile * 16 * EMBED;
        #pragma unroll
        for (int i = 0; i < 4; ++i)
            st[i] = *(const float4*)(vp + (i * 4 + srow) * EMBED + scol);
    }

    for (;;) {
        // convert + swizzled LDS write (each row's 512B: 2-way banks, free)
        #pragma unroll
        for (int i = 0; i < 4; ++i) {
            const int row = i * 4 + srow;
            const int idx = ((row << 8) + scol) ^ ((row & 7) << 3);
            *(s16x4*)(sA + idx) = (s16x4){ f2bf(st[i].x), f2bf(st[i].y),
                                           f2bf(st[i].z), f2bf(st[i].w) };
        }
        __syncthreads();

        const int r0   = tile * 16;
        const int next = tile + 512;
        if (next < 2720) {              // prefetch next tile under compute
            const float* __restrict__ vp = value + (size_t)next * 16 * EMBED;
            #pragma unroll
            for (int i = 0; i < 4; ++i)
                st[i] = *(const float4*)(vp + (i * 4 + srow) * EMBED + scol);
        }

        f32x4 acc[4] = {};
        #pragma unroll
        for (int kt = 0; kt < 8; ++kt) {
            const s16x8 a = *(const s16x8*)(sA + ((((c << 8) + kt * 32 + qd * 8)) ^ ((c & 7) << 3)));
            #pragma unroll
            for (int nt = 0; nt < 4; ++nt)
                acc[nt] = __builtin_amdgcn_mfma_f32_16x16x32_bf16(a, B[kt][nt], acc[nt], 0, 0, 0);
        }

        #pragma unroll
        for (int r = 0; r < 4; ++r) {
            const int grow = r0 + qd * 4 + r;
            const int n = (grow >= S_TOTAL) ? 1 : 0;
            const int s = grow - n * S_TOTAL;
            const float mk = vmask[grow];
            #pragma unroll
            for (int nt = 0; nt < 4; ++nt) {
                const int col = c0 + nt * 16 + c;
                const int hm = col >> 5, d = col & 31;
                v_out[((size_t)(n * M_HEADS + hm) * S_TOTAL + s) * DVAL + d] =
                    (u16)f2bf((acc[nt][r] + bias[nt]) * mk);
            }
        }
        __syncthreads();
        if (next >= 2720) break;
        tile = next;
    }
}

// ---------------------------------------------------------------------------
// Kernel 2 (split-bf16 MFMA): 64-rows-per-wave form — r13-verified WIN
// (182.6us total). Grid 256, 512 threads = 8 waves x 48 cols, each wave 64
// rows; B-stream halved vs 32-row form. LDS ~101KB union.
// ---------------------------------------------------------------------------
__global__ __launch_bounds__(512) void qproj_kernel(
    const float* __restrict__ queries,
    const float* __restrict__ qgl,
    const u16* __restrict__ Whi, const u16* __restrict__ Wlo,
    const float* __restrict__ b_off, const float* __restrict__ b_attn,
    float* __restrict__ pa)
{
    __shared__ __align__(16) char s_un[66560];   // union: {Ah,Al bf16 64KB} then {s_off fp32 [64][260]}
    __shared__ float s_attn[64][132];
    __shared__ float s_geom[64][4];

    u16* sAh = (u16*)s_un;                       // [64][256] swizzled
    u16* sAl = sAh + 16384;
    float (*s_off)[260] = (float(*)[260])s_un;

    const int t  = threadIdx.x;
    const int w  = t >> 6, l = t & 63;
    const int c  = l & 15, qd = l >> 4;
    const int row0 = blockIdx.x * 64;
    const int c0 = w * 48;

    if (t < 64) {
        const float* g = &qgl[(size_t)(row0 + t) * 4];
        s_geom[t][0] = 1.f / (1.f + __expf(-g[0]));
        s_geom[t][1] = 1.f / (1.f + __expf(-g[1]));
        s_geom[t][2] = (1.f / (1.f + __expf(-g[2]))) * 0.125f;
        s_geom[t][3] = (1.f / (1.f + __expf(-g[3]))) * 0.125f;
    }

    // ---- stage queries 64x256 fp32 -> hi/lo bf16 LDS, once per block ----
    {
        const int srow = t >> 6;        // + i*8
        const int scol = 4 * (t & 63);
        #pragma unroll
        for (int i = 0; i < 8; ++i) {
            const int row = i * 8 + srow;
            const float4 v = *(const float4*)(queries + (size_t)(row0 + row) * EMBED + scol);
            const short h0 = f2bf(v.x), h1 = f2bf(v.y), h2 = f2bf(v.z), h3 = f2bf(v.w);
            const int idx = ((row << 8) + scol) ^ ((row & 7) << 3);
            *(s16x4*)(sAh + idx) = (s16x4){ h0, h1, h2, h3 };
            *(s16x4*)(sAl + idx) = (s16x4){ f2bf(v.x - bf2f(h0)), f2bf(v.y - bf2f(h1)),
                                            f2bf(v.z - bf2f(h2)), f2bf(v.w - bf2f(h3)) };
        }
    }
    __syncthreads();

    f32x4 acc[4][3] = {};

    // ---- k-loop with 2-deep register double-buffered B prefetch ----
    s16x8 bhA[3], blA[3], bhB[3], blB[3];

    auto loadB = [&](int kt, s16x8 (&bh)[3], s16x8 (&bl)[3]) {
        #pragma unroll
        for (int nt = 0; nt < 3; ++nt) {
            const int idx = (((kt * 384 + c0 + nt * 16 + c) << 2) + qd) * 8;
            bh[nt] = *(const s16x8*)(Whi + idx);
            bl[nt] = *(const s16x8*)(Wlo + idx);
        }
    };
    auto stepK = [&](int kt, s16x8 (&bh)[3], s16x8 (&bl)[3]) {
        s16x8 ah[4], al[4];
        #pragma unroll
        for (int mt = 0; mt < 4; ++mt) {
            const int row = mt * 16 + c;
            const int idx = ((row << 8) + kt * 32 + qd * 8) ^ ((row & 7) << 3);
            ah[mt] = *(const s16x8*)(sAh + idx);
            al[mt] = *(const s16x8*)(sAl + idx);
        }
        #pragma unroll
        for (int mt = 0; mt < 4; ++mt)
            #pragma unroll
            for (int nt = 0; nt < 3; ++nt) {
                acc[mt][nt] = __builtin_amdgcn_mfma_f32_16x16x32_bf16(ah[mt], bh[nt], acc[mt][nt], 0, 0, 0);
                acc[mt][nt] = __builtin_amdgcn_mfma_f32_16x16x32_bf16(ah[mt], bl[nt], acc[mt][nt], 0, 0, 0);
                acc[mt][nt] = __builtin_amdgcn_mfma_f32_16x16x32_bf16(al[mt], bh[nt], acc[mt][nt], 0, 0, 0);
            }
    };

    loadB(0, bhA, blA);
    loadB(1, bhB, blB);
    #pragma unroll
    for (int kp = 0; kp < 4; ++kp) {
        stepK(2 * kp, bhA, blA);
        if (kp < 3) loadB(2 * kp + 2, bhA, blA);
        stepK(2 * kp + 1, bhB, blB);
        if (kp < 3) loadB(2 * kp + 3, bhB, blB);
    }
    __syncthreads();    // all LDS A-reads done before s_off overwrites staging

    #pragma unroll
    for (int mt = 0; mt < 4; ++mt)
        #pragma unroll
        for (int nt = 0; nt < 3; ++nt) {
            const int col = c0 + nt * 16 + c;
            #pragma unroll
            for (int r = 0; r < 4; ++r) {
                const int row = mt * 16 + qd * 4 + r;
                if (col < 256) s_off[row][col] = acc[mt][nt][r] + b_off[col];
                else           s_attn[row][col - 256] = acc[mt][nt][r] + b_attn[col - 256];
            }
        }
    __syncthreads();

    {   // 512 threads = exactly 64 rows x 8 heads softmax tasks
        const int qi = t >> 3, hm = t & 7;
        float* a = &s_attn[qi][hm * LK];
        float mx = a[0];
        #pragma unroll
        for (int i = 1; i < LK; ++i) mx = fmaxf(mx, a[i]);
        float s = 0.f;
        #pragma unroll
        for (int i = 0; i < LK; ++i) { const float e = __expf(a[i] - mx); a[i] = e; s += e; }
        const float inv = 1.f / s;
        #pragma unroll
        for (int i = 0; i < LK; ++i) a[i] *= inv;
    }
    __syncthreads();

    for (int p = t; p < 64 * 128; p += 512) {
        const int qi = p >> 7;
        const int pt = p & 127;
        const int lvl = (pt & 15) >> 2;
        const float Wl = (float)(128 >> lvl);
        const float px = fmaf(s_off[qi][2 * pt + 0], s_geom[qi][2], s_geom[qi][0]);
        const float py = fmaf(s_off[qi][2 * pt + 1], s_geom[qi][3], s_geom[qi][1]);
        const float gx = fminf(fmaxf(2.f * px - 1.f, -1.f), 1.f);
        const float gy = fminf(fmaxf(2.f * py - 1.f, -1.f), 1.f);
        const float x = (gx + 1.f) * (Wl * 0.5f) - 0.5f;
        const float y = (gy + 1.f) * (Wl * 0.5f) - 0.5f;
        const size_t idx = ((size_t)(row0 + qi) * 128 + pt) * 3;
        pa[idx + 0] = x;
        pa[idx + 1] = y;
        pa[idx + 2] = s_attn[qi][pt];
    }
}

// ---------------------------------------------------------------------------
// Kernel 3: bilinear sampling (r2-verified 4B-gather form). m = blk&7 keeps
// one head's slice L2-local per XCD. Characterized (r3, r11): L2-segment-
// throughput-bound — wider gathers and deeper explicit ILP both fail.
// ---------------------------------------------------------------------------
__global__ __launch_bounds__(256) void sample_kernel(
    const float* __restrict__ pa,
    const u16* __restrict__ v_tab,
    u16* __restrict__ mid)
{
    __shared__ int4   s_idx[QBS * 17];
    __shared__ float4 s_w[QBS * 17];

    const int t    = threadIdx.x;
    const int m    = blockIdx.x & 7;
    const int rest = blockIdx.x >> 3;
    const int qc   = rest & 511;
    const int n    = rest >> 9;
    const int q0   = qc * QBS;

    {
        const int qi = t >> 4, lk = t & 15;
        const int lvl   = lk >> 2;
        const int Wl    = 128 >> lvl;
        const int start = (lvl == 0) ? 0 : (lvl == 1) ? 16384 : (lvl == 2) ? 20480 : 21504;

        const size_t prow = ((size_t)(n * NQ + q0 + qi)) * 128 + m * 16 + lk;
        const float x  = pa[prow * 3 + 0];
        const float y  = pa[prow * 3 + 1];
        const float aw = pa[prow * 3 + 2];

        const float x0f = floorf(x), y0f = floorf(y);
        const int   x0 = (int)x0f, y0 = (int)y0f;
        const float wx = x - x0f, wy = y - y0f;

        const float vx0 = (x0 >= 0) ? 1.f : 0.f;
        const float vx1 = (x0 + 1 <= Wl - 1) ? 1.f : 0.f;
        const float vy0 = (y0 >= 0) ? 1.f : 0.f;
        const float vy1 = (y0 + 1 <= Wl - 1) ? 1.f : 0.f;

        const int xc0 = max(x0, 0);
        const int xc1 = min(x0 + 1, Wl - 1);
        const int yc0 = max(y0, 0);
        const int yc1 = min(y0 + 1, Wl - 1);

        const int e = qi * 17 + lk;
        s_idx[e] = make_int4((start + yc0 * Wl + xc0) * DVAL,
                             (start + yc0 * Wl + xc1) * DVAL,
                             (start + yc1 * Wl + xc0) * DVAL,
                             (start + yc1 * Wl + xc1) * DVAL);
        s_w[e] = make_float4(aw * (1.f - wx) * (1.f - wy) * vx0 * vy0,
                             aw * wx * (1.f - wy) * vx1 * vy0,
                             aw * (1.f - wx) * wy * vx0 * vy1,
                             aw * wx * wy * vx1 * vy1);
    }
    __syncthreads();

    const int g = t >> 4, dp = t & 15;
    const u16* __restrict__ vbp =
        v_tab + (size_t)(n * M_HEADS + m) * S_TOTAL * DVAL + 2 * dp;

    float acc0 = 0.f, acc1 = 0.f;
    #pragma unroll
    for (int lk = 0; lk < LK; ++lk) {
        const int4   id = s_idx[g * 17 + lk];
        const float4 w  = s_w[g * 17 + lk];
        const u32 u0 = *(const u32*)(vbp + id.x);
        const u32 u1 = *(const u32*)(vbp + id.y);
        const u32 u2 = *(const u32*)(vbp + id.z);
        const u32 u3 = *(const u32*)(vbp + id.w);
        acc0 = fmaf(w.x, __uint_as_float(u0 << 16), acc0);
        acc1 = fmaf(w.x, __uint_as_float(u0 & 0xffff0000u), acc1);
        acc0 = fmaf(w.y, __uint_as_float(u1 << 16), acc0);
        acc1 = fmaf(w.y, __uint_as_float(u1 & 0xffff0000u), acc1);
        acc0 = fmaf(w.z, __uint_as_float(u2 << 16), acc0);
        acc1 = fmaf(w.z, __uint_as_float(u2 & 0xffff0000u), acc1);
        acc0 = fmaf(w.w, __uint_as_float(u3 << 16), acc0);
        acc1 = fmaf(w.w, __uint_as_float(u3 & 0xffff0000u), acc1);
    }

    const u32 packed = ((u32)(u16)f2bf(acc1) << 16) | (u32)(u16)f2bf(acc0);
    *(u32*)(mid + ((size_t)(n * NQ + q0 + g)) * EMBED + m * DVAL + 2 * dp) = packed;
}

// ---------------------------------------------------------------------------
// Kernel 4 (MFMA, B-resident, LDS-staged A): out = mid @ W_out + b_out.
// r14: apply the twice-verified r8 staging recipe — previously all 4 waves
// re-read the same 8KB mid tile (4x duplicated latency-exposed L2 reads).
// Now the block stages it once (dense 32B/thread loads, already bf16, no
// conversion), swizzled LDS, ds_read_b128 fragments, next tile prefetched
// under compute. B-residency and accumulation order unchanged =>
// bit-identical.
// ---------------------------------------------------------------------------
__global__ __launch_bounds__(256, 2) void out_kernel(
    const u16* __restrict__ mid,
    const u16* __restrict__ Wpk,
    const float* __restrict__ b_out,
    float* __restrict__ out)
{
    __shared__ u16 sA[4096];            // 16 rows x 256 cols bf16, swizzled

    const int t  = threadIdx.x;
    const int w  = t >> 6, l = t & 63;
    const int c  = l & 15, qd = l >> 4;
    const int c0 = w * 64;

    s16x8 B[8][4];
    #pragma unroll
    for (int kt = 0; kt < 8; ++kt)
        #pragma unroll
        for (int nt = 0; nt < 4; ++nt)
            B[kt][nt] = *(const s16x8*)(Wpk + (((kt * 256 + c0 + nt * 16 + c) << 2) + qd) * 8);

    float bias[4];
    #pragma unroll
    for (int nt = 0; nt < 4; ++nt) bias[nt] = b_out[c0 + nt * 16 + c];

    // staging geometry: thread t covers u16 elems [t*16, t*16+16)
    const int srow = t >> 4;            // 0..15
    const int scol = (t & 15) * 16;     // 0..240 step 16

    int tile = blockIdx.x;
    s16x8 st0, st1;
    {
        const u16* __restrict__ mp = mid + (size_t)tile * 16 * EMBED;
        st0 = *(const s16x8*)(mp + srow * EMBED + scol);
        st1 = *(const s16x8*)(mp + srow * EMBED + scol + 8);
    }

    for (;;) {
        {
            const int i0 = ((srow << 8) + scol) ^ ((srow & 7) << 3);
            const int i1 = ((srow << 8) + scol + 8) ^ ((srow & 7) << 3);
            *(s16x8*)(sA + i0) = st0;
            *(s16x8*)(sA + i1) = st1;
        }
        __syncthreads();

        const int r0   = tile * 16;
        const int next = tile + 512;
        if (next < 1024) {              // prefetch next tile under compute
            const u16* __restrict__ mp = mid + (size_t)next * 16 * EMBED;
            st0 = *(const s16x8*)(mp + srow * EMBED + scol);
            st1 = *(const s16x8*)(mp + srow * EMBED + scol + 8);
        }

        f32x4 acc[4] = {};
        #pragma unroll
        for (int kt = 0; kt < 8; ++kt) {
            const s16x8 a = *(const s16x8*)(sA + (((c << 8) + kt * 32 + qd * 8) ^ ((c & 7) << 3)));
            #pragma unroll
            for (int nt = 0; nt < 4; ++nt)
                acc[nt] = __builtin_amdgcn_mfma_f32_16x16x32_bf16(a, B[kt][nt], acc[nt], 0, 0, 0);
        }

        #pragma unroll
        for (int r = 0; r < 4; ++r) {
            const int row = r0 + qd * 4 + r;
            #pragma unroll
            for (int nt = 0; nt < 4; ++nt)
                out[(size_t)row * EMBED + c0 + nt * 16 + c] = acc[nt][r] + bias[nt];
        }
        __syncthreads();
        if (next >= 1024) break;
        tile = next;
    }
}

// ---------------------------------------------------------------------------
extern "C" void kernel_launch(void* const* d_in, const int* in_sizes, int n_in,
                              void* d_out, int out_size, void* d_ws, size_t ws_size,
                              hipStream_t stream) {
    (void)in_sizes; (void)n_in; (void)out_size; (void)ws_size;

    const float* queries = (const float*)d_in[0];
    const float* qgl     = (const float*)d_in[1];
    const float* value   = (const float*)d_in[2];
    const float* vmask   = (const float*)d_in[3];
    const float* W_off   = (const float*)d_in[4];
    const float* b_off   = (const float*)d_in[5];
    const float* W_attn  = (const float*)d_in[6];
    const float* b_attn  = (const float*)d_in[7];
    const float* W_val   = (const float*)d_in[8];
    const float* b_val   = (const float*)d_in[9];
    const float* W_out   = (const float*)d_in[10];
    const float* b_out   = (const float*)d_in[11];

    float* ws   = (float*)d_ws;
    u16*  v_ws  = (u16*)(ws + V_OFF);
    float* pa   = ws + PA_OFF;
    u16*  mid   = (u16*)(ws + MID_OFF);
    u16*  whi   = (u16*)(ws + WHI_OFF);
    u16*  wlo   = (u16*)(ws + WLO_OFF);
    u16*  wvpk  = (u16*)(ws + WV_OFF);
    u16*  wopk  = (u16*)(ws + WO_OFF);
    float* outp = (float*)d_out;

    prep_kernel<<<896, 256, 0, stream>>>(W_off, W_attn, whi, wlo,
                                         W_val, wvpk, W_out, wopk);

    vproj_kernel<<<512, 256, 0, stream>>>(value, vmask, wvpk, b_val, v_ws);
    qproj_kernel<<<NROWS / 64, 512, 0, stream>>>(queries, qgl, whi, wlo,
                                                 b_off, b_attn, pa);
    sample_kernel<<<2 * (NQ / QBS) * M_HEADS, 256, 0, stream>>>(pa, v_ws, mid);
    out_kernel<<<512, 256, 0, stream>>>(mid, wopk, b_out, outp);
}